// Round 8
// baseline (647.603 us; speedup 1.0000x reference)
//
#include <hip/hip_runtime.h>

#define NB     16384
#define TEAM   5
#define NPAIR  20
#define UPAIR  10             // unordered pairs: prod/order2 are symmetric in (i,j)
#define PD     256
#define HD     256
#define H1D    512
#define NPLAY  (NB*TEAM)      // 81920
#define NCHUNK 1

typedef __attribute__((ext_vector_type(4))) float f32x4;
typedef __attribute__((ext_vector_type(8))) short s16x8;

__device__ __forceinline__ float silu_f(float x){ return x / (1.0f + __expf(-x)); }

__device__ __forceinline__ unsigned short bf16_rne(float x){
  unsigned u = __float_as_uint(x);
  unsigned r = u + 0x7fffu + ((u >> 16) & 1u);
  return (unsigned short)(r >> 16);
}
__device__ __forceinline__ float bf16_to_f(unsigned short s){
  return __uint_as_float(((unsigned)s) << 16);
}
// truncation split: hi = trunc16(x), lo = trunc16(x - hi). Validated r3-r7
// (absmax 5.96e-8, passes). 4 VALU/elem vs 10 for double-RNE.
__device__ __forceinline__ void tsplit(float x, short& h, short& l){
  const unsigned u = __float_as_uint(x);
  h = (short)(u >> 16);
  const float lf = x - __uint_as_float(u & 0xffff0000u);
  l = (short)(__float_as_uint(lf) >> 16);
}

// ---------------------------------------------------------------------------
// Generic prep: pack an N x K fp32 row-major matrix into MFMA B-fragment
// order, split bf16 hi/lo.
// ---------------------------------------------------------------------------
__global__ void k_pack(const float* __restrict__ w, short* __restrict__ wf,
                       int KT, int total)
{
  const int tid = blockIdx.x * 256 + threadIdx.x;
  if (tid >= total) return;
  const int slot = tid & 7;
  const int lane = (tid >> 3) & 63;
  const int grp  = tid >> 9;
  const int kt   = grp % KT;
  const int nt   = grp / KT;
  const int K    = KT * 32;
  const int n = nt * 16 + (lane & 15);
  const int k = kt * 32 + ((lane >> 4) << 3) + slot;
  const float v = w[(size_t)n * K + k];
  const unsigned short hi = bf16_rne(v);
  const float lo = v - bf16_to_f(hi);
  wf[tid]         = (short)hi;
  wf[total + tid] = (short)bf16_rne(lo);
}

// ---------------------------------------------------------------------------
// k_l1 (round-16): cy=2 / acc[5][4] shape (proven best) + T14 async-split
// pipeline: double-buffered Af, ONE barrier per K64 chunk; chunk kc+1's
// global loads (emb gather, ~L3 latency) issue before MFMA(kc) and convert
// at the top of the next iteration -- latency hides under the MFMA phase.
// Register math: ~204 unified + 20 in-flight = ~224 < 256 -> occupancy
// unchanged (unlike k_mlp's r4 spill at 160-acc). Tripwire: WRITE_SIZE
// excess >20% over the legit 168 MB (Hh1) = spill -> revert.
// ---------------------------------------------------------------------------
__global__ __launch_bounds__(256) void k_l1(
    const int* __restrict__ tids, const float* __restrict__ emb,
    const short* __restrict__ w1f, const float* __restrict__ b1,
    float* __restrict__ Hh1)
{
  __shared__ short Af[2][10240];   // dbuf: hi at 0, lo at +5120 (each 20.5 KB)
  __shared__ float Bb[256];
  __shared__ int   Tid[80];

  const int t = threadIdx.x, lane = t & 63, w = t >> 6;
  const int bx = blockIdx.x, cy = blockIdx.y;
  const int p0 = bx * 80;

  if (t < 80) Tid[t] = tids[p0 + t];
  Bb[t] = b1[cy * 256 + t];
  __syncthreads();                    // Tid ready for hoisted row offsets

  // hoisted staging geometry (invariant per thread; mt_ == f)
  const int sg    = (t & 1) * 4;
  const int lane_ = (t >> 1) & 63;
  const int ks_   = (t >> 7) & 1;
  const int kb    = ks_ * 32 + ((lane_ >> 4) << 3) + sg;
  int rowE[5], aof[5];
  #pragma unroll
  for (int f = 0; f < 5; ++f) {
    rowE[f] = Tid[f * 16 + (lane_ & 15)] * PD;
    aof[f]  = (f * 2 + ks_) * 512 + lane_ * 8 + sg;
  }

  f32x4 acc[5][4];
  #pragma unroll
  for (int mt = 0; mt < 5; ++mt)
    #pragma unroll
    for (int j = 0; j < 4; ++j) acc[mt][j] = (f32x4){0.f,0.f,0.f,0.f};

  const s16x8* Bh = reinterpret_cast<const s16x8*>(w1f);   // hi; lo at +16384 units

  // prologue: loads for chunk 0
  float4 ld[5];
  #pragma unroll
  for (int f = 0; f < 5; ++f)
    ld[f] = *reinterpret_cast<const float4*>(emb + rowE[f] + kb);

  for (int kc = 0; kc < 4; ++kc) {
    short* buf = Af[kc & 1];
    // convert + write the landed chunk
    #pragma unroll
    for (int f = 0; f < 5; ++f) {
      float pv[4] = {ld[f].x, ld[f].y, ld[f].z, ld[f].w};
      short hi[4], lo[4];
      #pragma unroll
      for (int e = 0; e < 4; ++e) tsplit(pv[e], hi[e], lo[e]);
      *reinterpret_cast<short4*>(&buf[aof[f]])        = make_short4(hi[0],hi[1],hi[2],hi[3]);
      *reinterpret_cast<short4*>(&buf[5120 + aof[f]]) = make_short4(lo[0],lo[1],lo[2],lo[3]);
    }
    // issue next chunk's loads (in flight across MFMA below)
    if (kc < 3) {
      const int kk = (kc + 1) * 64 + kb;
      #pragma unroll
      for (int f = 0; f < 5; ++f)
        ld[f] = *reinterpret_cast<const float4*>(emb + rowE[f] + kk);
    }
    __syncthreads();                 // buf writes visible; safe vs kc-1 reads (dbuf)

    #pragma unroll
    for (int ks = 0; ks < 2; ++ks) {
      const int kt = kc * 2 + ks;
      s16x8 ah[5], al[5];
      #pragma unroll
      for (int mt = 0; mt < 5; ++mt) {
        ah[mt] = *reinterpret_cast<const s16x8*>(&buf[(mt*2 + ks)*512 + lane*8]);
        al[mt] = *reinterpret_cast<const s16x8*>(&buf[5120 + (mt*2 + ks)*512 + lane*8]);
      }
      #pragma unroll
      for (int j = 0; j < 4; ++j) {
        const int nt = cy * 16 + w * 4 + j;
        const s16x8 bh = Bh[(nt*8 + kt)*64 + lane];
        const s16x8 bl = Bh[16384 + (nt*8 + kt)*64 + lane];
        #pragma unroll
        for (int mt = 0; mt < 5; ++mt) {
          acc[mt][j] = __builtin_amdgcn_mfma_f32_16x16x32_bf16(ah[mt], bh, acc[mt][j], 0,0,0);
          acc[mt][j] = __builtin_amdgcn_mfma_f32_16x16x32_bf16(al[mt], bh, acc[mt][j], 0,0,0);
          acc[mt][j] = __builtin_amdgcn_mfma_f32_16x16x32_bf16(ah[mt], bl, acc[mt][j], 0,0,0);
        }
      }
    }
  }

  // epilogue: bias + silu -> Hh1 fp32 C-layout
  #pragma unroll
  for (int mt = 0; mt < 5; ++mt)
    #pragma unroll
    for (int j = 0; j < 4; ++j) {
      const int nl = w * 64 + j * 16 + (lane & 15);
      const int n  = cy * 256 + nl;
      #pragma unroll
      for (int r = 0; r < 4; ++r) {
        const int p = p0 + mt*16 + ((lane >> 4) << 2) + r;
        Hh1[(size_t)p * H1D + n] = silu_f(acc[mt][j][r] + Bb[nl]);
      }
    }
}

// ---------------------------------------------------------------------------
// k_l2 (round-16): same T14 async-split dbuf pipeline, 8 chunks (K=512).
// Source = Hh1 stream (168 MB, HBM/L3 latency) -- most to gain from hiding.
// Tripwire: WRITE_SIZE excess >20% over legit 84 MB (H) = spill -> revert.
// ---------------------------------------------------------------------------
__global__ __launch_bounds__(256) void k_l2(
    const float* __restrict__ Hh1, const short* __restrict__ w2f,
    const float* __restrict__ b2, float* __restrict__ Hout)
{
  __shared__ short Af[2][10240];   // dbuf
  __shared__ float Bb[256];

  const int t = threadIdx.x, lane = t & 63, w = t >> 6;
  const int bx = blockIdx.x;
  const int p0 = bx * 80;

  Bb[t] = b2[t];

  const int sg    = (t & 1) * 4;
  const int lane_ = (t >> 1) & 63;
  const int ks_   = (t >> 7) & 1;
  const int kb    = ks_ * 32 + ((lane_ >> 4) << 3) + sg;
  int rowH[5], aof[5];
  #pragma unroll
  for (int f = 0; f < 5; ++f) {
    rowH[f] = (p0 + f * 16 + (lane_ & 15)) * H1D;
    aof[f]  = (f * 2 + ks_) * 512 + lane_ * 8 + sg;
  }

  f32x4 acc[5][4];
  #pragma unroll
  for (int mt = 0; mt < 5; ++mt)
    #pragma unroll
    for (int j = 0; j < 4; ++j) acc[mt][j] = (f32x4){0.f,0.f,0.f,0.f};

  const s16x8* B2 = reinterpret_cast<const s16x8*>(w2f);   // hi; lo at +16384 units

  // prologue: loads for chunk 0
  float4 ld[5];
  #pragma unroll
  for (int f = 0; f < 5; ++f)
    ld[f] = *reinterpret_cast<const float4*>(Hh1 + rowH[f] + kb);

  for (int kc = 0; kc < 8; ++kc) {
    short* buf = Af[kc & 1];
    #pragma unroll
    for (int f = 0; f < 5; ++f) {
      float pv[4] = {ld[f].x, ld[f].y, ld[f].z, ld[f].w};
      short hi[4], lo[4];
      #pragma unroll
      for (int e = 0; e < 4; ++e) tsplit(pv[e], hi[e], lo[e]);
      *reinterpret_cast<short4*>(&buf[aof[f]])        = make_short4(hi[0],hi[1],hi[2],hi[3]);
      *reinterpret_cast<short4*>(&buf[5120 + aof[f]]) = make_short4(lo[0],lo[1],lo[2],lo[3]);
    }
    if (kc < 7) {
      const int kk = (kc + 1) * 64 + kb;
      #pragma unroll
      for (int f = 0; f < 5; ++f)
        ld[f] = *reinterpret_cast<const float4*>(Hh1 + rowH[f] + kk);
    }
    __syncthreads();

    #pragma unroll
    for (int ks = 0; ks < 2; ++ks) {
      const int kt = kc * 2 + ks;
      s16x8 ah[5], al[5];
      #pragma unroll
      for (int mt = 0; mt < 5; ++mt) {
        ah[mt] = *reinterpret_cast<const s16x8*>(&buf[(mt*2 + ks)*512 + lane*8]);
        al[mt] = *reinterpret_cast<const s16x8*>(&buf[5120 + (mt*2 + ks)*512 + lane*8]);
      }
      #pragma unroll
      for (int j = 0; j < 4; ++j) {
        const int nt = w * 4 + j;
        const s16x8 bh = B2[(nt*16 + kt)*64 + lane];
        const s16x8 bl = B2[16384 + (nt*16 + kt)*64 + lane];
        #pragma unroll
        for (int mt = 0; mt < 5; ++mt) {
          acc[mt][j] = __builtin_amdgcn_mfma_f32_16x16x32_bf16(ah[mt], bh, acc[mt][j], 0,0,0);
          acc[mt][j] = __builtin_amdgcn_mfma_f32_16x16x32_bf16(al[mt], bh, acc[mt][j], 0,0,0);
          acc[mt][j] = __builtin_amdgcn_mfma_f32_16x16x32_bf16(ah[mt], bl, acc[mt][j], 0,0,0);
        }
      }
    }
  }

  // epilogue: +b2, C-layout store
  #pragma unroll
  for (int mt = 0; mt < 5; ++mt)
    #pragma unroll
    for (int j = 0; j < 4; ++j) {
      const int n = w * 64 + j * 16 + (lane & 15);
      #pragma unroll
      for (int r = 0; r < 4; ++r) {
        const int p = p0 + mt*16 + ((lane >> 4) << 2) + r;
        Hout[(size_t)p * PD + n] = acc[mt][j][r] + Bb[n];
      }
    }
}

// ---------------------------------------------------------------------------
// Kernel A v4 (FALLBACK when ws too small for the split): unchanged.
// ---------------------------------------------------------------------------
__global__ __launch_bounds__(256) void k_fm4(
    const int* __restrict__ tids, const float* __restrict__ emb,
    const short* __restrict__ w1f, const float* __restrict__ b1,
    const short* __restrict__ w2f, const float* __restrict__ b2,
    float* __restrict__ Hout)
{
  __shared__ char smem[65536 + 3072];
  short* Af  = reinterpret_cast<short*>(smem);
  short* H1f = reinterpret_cast<short*>(smem);
  float* Bb  = reinterpret_cast<float*>(smem + 65536);

  const int t = threadIdx.x, lane = t & 63, w = t >> 6;
  const int m0 = blockIdx.x * 32;

  Bb[t]       = b1[t];
  Bb[t + 256] = b1[t + 256];
  Bb[t + 512] = b2[t];

  #pragma unroll
  for (int f = 0; f < 8; ++f) {
    const int g     = t + f * 256;
    const int sg    = (g & 1) * 4;
    const int lane_ = (g >> 1) & 63;
    const int kt_   = (g >> 7) & 7;
    const int mt_   = g >> 10;
    const int p     = mt_ * 16 + (lane_ & 15);
    const int k     = kt_ * 32 + ((lane_ >> 4) << 3) + sg;
    const int row   = tids[m0 + p];
    const float4 a4 = *reinterpret_cast<const float4*>(emb + (size_t)row * PD + k);
    float pv[4] = {a4.x, a4.y, a4.z, a4.w};
    short hi[4], lo[4];
    #pragma unroll
    for (int e = 0; e < 4; ++e) {
      const unsigned short h = bf16_rne(pv[e]);
      hi[e] = (short)h;
      lo[e] = (short)bf16_rne(pv[e] - bf16_to_f(h));
    }
    const int off = ((mt_*8 + kt_)*64 + lane_)*8 + sg;
    *reinterpret_cast<short4*>(&Af[off])        = make_short4(hi[0],hi[1],hi[2],hi[3]);
    *reinterpret_cast<short4*>(&Af[8192 + off]) = make_short4(lo[0],lo[1],lo[2],lo[3]);
  }
  __syncthreads();

  const s16x8* B1 = reinterpret_cast<const s16x8*>(w1f);
  const s16x8* B2 = reinterpret_cast<const s16x8*>(w2f);

  f32x4 acc1[2][8];
  #pragma unroll
  for (int mt = 0; mt < 2; ++mt)
    #pragma unroll
    for (int j = 0; j < 8; ++j) acc1[mt][j] = (f32x4){0.f,0.f,0.f,0.f};

  #pragma unroll
  for (int kt = 0; kt < 8; ++kt) {
    s16x8 ah[2], al[2];
    #pragma unroll
    for (int mt = 0; mt < 2; ++mt) {
      ah[mt] = *reinterpret_cast<const s16x8*>(&Af[((mt*8 + kt)*64 + lane)*8]);
      al[mt] = *reinterpret_cast<const s16x8*>(&Af[8192 + ((mt*8 + kt)*64 + lane)*8]);
    }
    #pragma unroll
    for (int j = 0; j < 8; ++j) {
      const int nt = w * 8 + j;
      const s16x8 bh = B1[(nt*8 + kt)*64 + lane];
      const s16x8 bl = B1[16384 + (nt*8 + kt)*64 + lane];
      #pragma unroll
      for (int mt = 0; mt < 2; ++mt) {
        acc1[mt][j] = __builtin_amdgcn_mfma_f32_16x16x32_bf16(ah[mt], bh, acc1[mt][j], 0,0,0);
        acc1[mt][j] = __builtin_amdgcn_mfma_f32_16x16x32_bf16(al[mt], bh, acc1[mt][j], 0,0,0);
        acc1[mt][j] = __builtin_amdgcn_mfma_f32_16x16x32_bf16(ah[mt], bl, acc1[mt][j], 0,0,0);
      }
    }
  }
  __syncthreads();

  #pragma unroll
  for (int mt = 0; mt < 2; ++mt)
    #pragma unroll
    for (int j = 0; j < 8; ++j) {
      const int n     = w * 128 + j * 16 + (lane & 15);
      const int kt2   = n >> 5;
      const int lhalf = 16 * ((n >> 3) & 3);
      const int slot2 = n & 7;
      #pragma unroll
      for (int r = 0; r < 4; ++r) {
        const int prow = ((lane >> 4) << 2) + r;
        const float v = silu_f(acc1[mt][j][r] + Bb[n]);
        const unsigned short hi = bf16_rne(v);
        const int off = ((mt*16 + kt2)*64 + lhalf + prow)*8 + slot2;
        H1f[off]         = (short)hi;
        H1f[16384 + off] = (short)bf16_rne(v - bf16_to_f(hi));
      }
    }
  __syncthreads();

  f32x4 acc2[2][4];
  #pragma unroll
  for (int mt = 0; mt < 2; ++mt)
    #pragma unroll
    for (int j = 0; j < 4; ++j) acc2[mt][j] = (f32x4){0.f,0.f,0.f,0.f};

  #pragma unroll
  for (int kt = 0; kt < 16; ++kt) {
    s16x8 ah[2], al[2];
    #pragma unroll
    for (int mt = 0; mt < 2; ++mt) {
      ah[mt] = *reinterpret_cast<const s16x8*>(&H1f[((mt*16 + kt)*64 + lane)*8]);
      al[mt] = *reinterpret_cast<const s16x8*>(&H1f[16384 + ((mt*16 + kt)*64 + lane)*8]);
    }
    #pragma unroll
    for (int j = 0; j < 4; ++j) {
      const int nt = w * 4 + j;
      const s16x8 bh = B2[(nt*16 + kt)*64 + lane];
      const s16x8 bl = B2[16384 + (nt*16 + kt)*64 + lane];
      #pragma unroll
      for (int mt = 0; mt < 2; ++mt) {
        acc2[mt][j] = __builtin_amdgcn_mfma_f32_16x16x32_bf16(ah[mt], bh, acc2[mt][j], 0,0,0);
        acc2[mt][j] = __builtin_amdgcn_mfma_f32_16x16x32_bf16(al[mt], bh, acc2[mt][j], 0,0,0);
        acc2[mt][j] = __builtin_amdgcn_mfma_f32_16x16x32_bf16(ah[mt], bl, acc2[mt][j], 0,0,0);
      }
    }
  }

  #pragma unroll
  for (int mt = 0; mt < 2; ++mt)
    #pragma unroll
    for (int j = 0; j < 4; ++j) {
      const int n = w * 64 + j * 16 + (lane & 15);
      #pragma unroll
      for (int r = 0; r < 4; ++r) {
        const int p = m0 + mt*16 + ((lane >> 4) << 2) + r;
        Hout[(size_t)p * PD + n] = acc2[mt][j][r] + Bb[512 + n];
      }
    }
}

// ---------------------------------------------------------------------------
// Kernel B v3.2: att+score; trunc-split staging. (unchanged from 602 build)
// ---------------------------------------------------------------------------
__global__ __launch_bounds__(256) void k_score(
    const float* __restrict__ Hin, const short* __restrict__ attf,
    const float* __restrict__ attb, float* __restrict__ SC)
{
  __shared__ char smem[49152 + 1024];
  short* Hf  = reinterpret_cast<short*>(smem);
  float* WAl = reinterpret_cast<float*>(smem);
  float* Ab  = reinterpret_cast<float*>(smem + 49152);

  const int t = threadIdx.x, lane = t & 63, w = t >> 6;
  const int b0 = blockIdx.x * 8;
  const float* src = Hin + (size_t)b0 * TEAM * PD;

  Ab[t] = attb[t];

  #pragma unroll
  for (int f = 0; f < 12; ++f) {
    const int g     = t + f * 256;
    const int sg    = (g & 1) * 4;
    const int lane_ = (g >> 1) & 63;
    const int kt_   = (g >> 7) & 7;
    const int mt_   = g >> 10;
    const int p     = mt_ * 16 + (lane_ & 15);
    const int k     = kt_ * 32 + ((lane_ >> 4) << 3) + sg;
    float4 a4 = make_float4(0.f, 0.f, 0.f, 0.f);
    if (p < 40) a4 = *reinterpret_cast<const float4*>(src + (size_t)p * PD + k);
    float pv[4] = {a4.x, a4.y, a4.z, a4.w};
    short hi[4], lo[4];
    #pragma unroll
    for (int e = 0; e < 4; ++e) tsplit(pv[e], hi[e], lo[e]);
    const int off = ((mt_*8 + kt_)*64 + lane_)*8 + sg;
    *reinterpret_cast<short4*>(&Hf[off])         = make_short4(hi[0],hi[1],hi[2],hi[3]);
    *reinterpret_cast<short4*>(&Hf[12288 + off]) = make_short4(lo[0],lo[1],lo[2],lo[3]);
  }
  __syncthreads();

  f32x4 acc[3][4];
  #pragma unroll
  for (int mt = 0; mt < 3; ++mt)
    #pragma unroll
    for (int j = 0; j < 4; ++j) acc[mt][j] = (f32x4){0.f,0.f,0.f,0.f};

  const s16x8* Bh = reinterpret_cast<const s16x8*>(attf);
  #pragma unroll
  for (int kt = 0; kt < 8; ++kt) {
    s16x8 ah[3], al[3];
    #pragma unroll
    for (int mt = 0; mt < 3; ++mt) {
      ah[mt] = *reinterpret_cast<const s16x8*>(&Hf[((mt*8 + kt)*64 + lane)*8]);
      al[mt] = *reinterpret_cast<const s16x8*>(&Hf[12288 + ((mt*8 + kt)*64 + lane)*8]);
    }
    #pragma unroll
    for (int j = 0; j < 4; ++j) {
      const int nt = w * 4 + j;
      const s16x8 bh = Bh[(nt*8 + kt)*64 + lane];
      const s16x8 bl = Bh[8192 + (nt*8 + kt)*64 + lane];
      #pragma unroll
      for (int mt = 0; mt < 3; ++mt) {
        acc[mt][j] = __builtin_amdgcn_mfma_f32_16x16x32_bf16(ah[mt], bh, acc[mt][j], 0,0,0);
        acc[mt][j] = __builtin_amdgcn_mfma_f32_16x16x32_bf16(al[mt], bh, acc[mt][j], 0,0,0);
        acc[mt][j] = __builtin_amdgcn_mfma_f32_16x16x32_bf16(ah[mt], bl, acc[mt][j], 0,0,0);
      }
    }
  }
  __syncthreads();

  #pragma unroll
  for (int mt = 0; mt < 3; ++mt)
    #pragma unroll
    for (int j = 0; j < 4; ++j) {
      const int n = w * 64 + j * 16 + (lane & 15);
      #pragma unroll
      for (int r = 0; r < 4; ++r) {
        const int row = mt * 16 + ((lane >> 4) << 2) + r;
        if (row < 40) WAl[row * 260 + n] = acc[mt][j][r] + Ab[n];
      }
    }
  __syncthreads();

  #pragma unroll
  for (int qq = 0; qq < 2; ++qq) {
    const int q = w * 2 + qq;
    #pragma unroll
    for (int p = 0; p < NPAIR; ++p) {
      const int i1 = p >> 2, jj = p & 3;
      const int i2 = jj + (jj >= i1 ? 1 : 0);
      const float4 a4 = *reinterpret_cast<const float4*>(WAl + (q*TEAM + i1) * 260 + lane * 4);
      const float4 b4 = *reinterpret_cast<const float4*>(src + (size_t)(q*TEAM + i2) * PD + lane * 4);
      float v = a4.x*b4.x + a4.y*b4.y + a4.z*b4.z + a4.w*b4.w;
      #pragma unroll
      for (int off = 32; off > 0; off >>= 1) v += __shfl_xor(v, off);
      if (lane == 0) SC[(size_t)(b0 + q) * NPAIR + p] = v;
    }
  }
}

// ---------------------------------------------------------------------------
// Kernel C: pair MLP -- unchanged from the 602-us build (r7). 189 us, reg-
// bound; no headroom for pipelining (r4 spill proof). Tripwire stands.
// ---------------------------------------------------------------------------
__global__ __launch_bounds__(256, 2) void k_mlp(
    const float* __restrict__ Hin, const short* __restrict__ w1f,
    const float* __restrict__ b1, const float* __restrict__ w2,
    float* __restrict__ PART)
{
  __shared__ float Hl[40*260];      // 41.6 KB
  __shared__ short Af[10240];       // 20.5 KB (hi at 0, lo at +5120)
  __shared__ float Wb[512];
  __shared__ float Ww[512];

  const int t    = threadIdx.x;
  const int lane = t & 63;
  const int w    = t >> 6;
  const int blkx = blockIdx.x;
  const int b0   = blkx * 8;
  const float* src = Hin + (size_t)b0 * TEAM * PD;

  {
    #pragma unroll
    for (int rep = 0; rep < 10; ++rep) {
      const int flat = t + rep * 256;
      const int row = flat >> 6, c4 = (flat & 63) * 4;
      *reinterpret_cast<float4*>(Hl + row * 260 + c4) =
        *reinterpret_cast<const float4*>(src + (size_t)row * PD + c4);
    }
    Wb[t]       = b1[t];
    Wb[t + 256] = b1[t + 256];
    Ww[t]       = w2[t];
    Ww[t + 256] = w2[t + 256];
  }

  // hoisted staging geometry (invariant per thread; mt_ == f)
  const int sg    = (t & 1) * 4;
  const int lane_ = (t >> 1) & 63;
  const int ks_   = (t >> 7) & 1;
  const int kb    = ks_ * 32 + ((lane_ >> 4) << 3) + sg;
  int rowA[5], rowB[5], aof[5];
  #pragma unroll
  for (int f = 0; f < 5; ++f) {
    const int r  = f * 16 + (lane_ & 15);       // pair-row 0..79
    const int q  = r / UPAIR;
    const int p  = r - q * UPAIR;
    const int i1 = (p >= 4) + (p >= 7) + (p >= 9);
    const int i2 = p - (i1 * (9 - i1)) / 2 + i1 + 1;
    rowA[f] = (q * TEAM + i1) * 260;
    rowB[f] = (q * TEAM + i2) * 260;
    aof[f]  = (f * 2 + ks_) * 512 + lane_ * 8 + sg;
  }

  f32x4 acc[5][8];
  #pragma unroll
  for (int mt = 0; mt < 5; ++mt)
    #pragma unroll
    for (int j = 0; j < 8; ++j) acc[mt][j] = (f32x4){0.f,0.f,0.f,0.f};

  const s16x8* Bh = reinterpret_cast<const s16x8*>(w1f);
  const s16x8* Bl = reinterpret_cast<const s16x8*>(w1f + 131072);
  const int nt0 = w * 8;

  for (int kt = 0; kt < 8; ++kt) {
    const int kc = kt >> 1, ks = kt & 1;
    if (ks == 0) {
      __syncthreads();              // Hl fill done (kt=0) / prev chunk reads done
      const int kk = kc * 64 + kb;
      #pragma unroll
      for (int f = 0; f < 5; ++f) {
        const float4 a4 = *reinterpret_cast<const float4*>(Hl + rowA[f] + kk);
        const float4 b4 = *reinterpret_cast<const float4*>(Hl + rowB[f] + kk);
        float pv[4] = {a4.x*b4.x, a4.y*b4.y, a4.z*b4.z, a4.w*b4.w};
        short hi[4], lo[4];
        #pragma unroll
        for (int e = 0; e < 4; ++e) tsplit(pv[e], hi[e], lo[e]);
        *reinterpret_cast<short4*>(&Af[aof[f]])        = make_short4(hi[0],hi[1],hi[2],hi[3]);
        *reinterpret_cast<short4*>(&Af[5120 + aof[f]]) = make_short4(lo[0],lo[1],lo[2],lo[3]);
      }
      __syncthreads();
    }

    s16x8 ah[5], al[5];
    #pragma unroll
    for (int mt = 0; mt < 5; ++mt) {
      ah[mt] = *reinterpret_cast<const s16x8*>(&Af[(mt*2 + ks)*512 + lane*8]);
      al[mt] = *reinterpret_cast<const s16x8*>(&Af[5120 + (mt*2 + ks)*512 + lane*8]);
    }
    #pragma unroll
    for (int j = 0; j < 8; ++j) {
      const s16x8 bh = Bh[((nt0 + j)*8 + kt)*64 + lane];
      const s16x8 bl = Bl[((nt0 + j)*8 + kt)*64 + lane];
      #pragma unroll
      for (int mt = 0; mt < 5; ++mt) {
        acc[mt][j] = __builtin_amdgcn_mfma_f32_16x16x32_bf16(ah[mt], bh, acc[mt][j], 0,0,0);
        acc[mt][j] = __builtin_amdgcn_mfma_f32_16x16x32_bf16(ah[mt], bl, acc[mt][j], 0,0,0);
        acc[mt][j] = __builtin_amdgcn_mfma_f32_16x16x32_bf16(al[mt], bh, acc[mt][j], 0,0,0);
      }
    }
  }

  __syncthreads();
  float* red = reinterpret_cast<float*>(Af);

  const int colbase = w * 128 + (lane & 15);
  #pragma unroll
  for (int mt = 0; mt < 5; ++mt)
    #pragma unroll
    for (int r = 0; r < 4; ++r) {
      float s = 0.0f;
      #pragma unroll
      for (int j = 0; j < 8; ++j) {
        const int c = colbase + j * 16;
        s += silu_f(acc[mt][j][r] + Wb[c]) * Ww[c];
      }
      s += __shfl_xor(s, 1); s += __shfl_xor(s, 2);
      s += __shfl_xor(s, 4); s += __shfl_xor(s, 8);
      if ((lane & 15) == 0) {
        const int row = mt * 16 + ((lane >> 4) << 2) + r;
        red[row * 4 + w] = s;
      }
    }
  __syncthreads();
  if (t < 80) {
    const float s = red[t*4] + red[t*4+1] + red[t*4+2] + red[t*4+3];
    PART[(size_t)blkx * 80 + t] = s;
  }
}

// ---------------------------------------------------------------------------
// Kernel D: one thread per batch.
// ---------------------------------------------------------------------------
__global__ void k_final(const float* __restrict__ SC, const float* __restrict__ PART,
                        const float* __restrict__ mb2, float* __restrict__ out)
{
  const int b = blockIdx.x * 256 + threadIdx.x;
  if (b >= NB) return;
  const float bias2 = mb2[0];
  float ord[UPAIR];
  #pragma unroll
  for (int u = 0; u < UPAIR; ++u) {
    float s = bias2;
    #pragma unroll
    for (int g = 0; g < NCHUNK; ++g) s += PART[(size_t)g * (NB*UPAIR) + (size_t)b * UPAIR + u];
    ord[u] = s;
  }
  float sc[NPAIR];
  #pragma unroll
  for (int p = 0; p < NPAIR; ++p) sc[p] = SC[(size_t)b * NPAIR + p];

  float res = 0.0f;
  #pragma unroll
  for (int i = 0; i < TEAM; ++i) {
    float m = sc[4*i];
    #pragma unroll
    for (int jj = 1; jj < 4; ++jj) m = fmaxf(m, sc[4*i + jj]);
    float e[4], d = 0.0f;
    #pragma unroll
    for (int jj = 0; jj < 4; ++jj) { e[jj] = __expf(sc[4*i + jj] - m); d += e[jj]; }
    const float inv = 1.0f / d;
    #pragma unroll
    for (int jj = 0; jj < 4; ++jj) {
      const int i2 = jj + (jj >= i ? 1 : 0);
      const int a  = i < i2 ? i : i2;
      const int bb = i < i2 ? i2 : i;
      const int u  = (a * (9 - a)) / 2 + (bb - a - 1);
      res += ord[u] * e[jj] * inv;
    }
  }
  out[b] = res;
}

// ---------------------------------------------------------------------------
extern "C" void kernel_launch(void* const* d_in, const int* in_sizes, int n_in,
                              void* d_out, int out_size, void* d_ws, size_t ws_size,
                              hipStream_t stream)
{
  (void)in_sizes; (void)n_in; (void)out_size;
  const int*   tids = (const int*)  d_in[0];
  const float* emb  = (const float*)d_in[1];
  const float* fw1  = (const float*)d_in[2];
  const float* fb1  = (const float*)d_in[3];
  const float* fw2  = (const float*)d_in[4];
  const float* fb2  = (const float*)d_in[5];
  const float* attw = (const float*)d_in[6];
  const float* attb = (const float*)d_in[7];
  const float* mw1  = (const float*)d_in[8];
  const float* mb1  = (const float*)d_in[9];
  const float* mw2  = (const float*)d_in[10];
  const float* mb2  = (const float*)d_in[11];
  float* out = (float*)d_out;

  float* H     = (float*)d_ws;                        // 81920*256 f32 = 84 MB
  float* SC    = H + (size_t)NPLAY * PD;              // NB*20 f32
  float* PART  = SC + (size_t)NB * NPAIR;             // NCHUNK*NB*10 f32
  short* w1f_m = (short*)(PART + (size_t)NCHUNK * NB * UPAIR); // mlp_w1 packed
  short* w1f_f = w1f_m + 262144;                      // fm_w1 packed
  short* w2f_f = w1f_f + 262144;                      // fm_w2 packed
  short* attf  = w2f_f + 262144;                      // att_w packed
  float* Hh1   = (float*)(attf + 131072);             // 81920*512 f32 = 168 MB
  const size_t NEED = (size_t)((char*)(Hh1 + (size_t)NPLAY * H1D) - (char*)d_ws);

  k_pack<<<512, 256, 0, stream>>>(mw1, w1f_m, 8, 131072);   // 512x256
  k_pack<<<512, 256, 0, stream>>>(fw1, w1f_f, 8, 131072);   // 512x256
  k_pack<<<512, 256, 0, stream>>>(fw2, w2f_f, 16, 131072);  // 256x512
  k_pack<<<256, 256, 0, stream>>>(attw, attf, 8, 65536);    // 256x256

  if (ws_size >= NEED) {
    k_l1<<<dim3(NPLAY/80, 2), 256, 0, stream>>>(tids, emb, w1f_f, fb1, Hh1);
    k_l2<<<NPLAY/80, 256, 0, stream>>>(Hh1, w2f_f, fb2, H);
  } else {
    k_fm4<<<NPLAY/32, 256, 0, stream>>>(tids, emb, w1f_f, fb1, w2f_f, fb2, H);
  }
  k_score<<<NB/8, 256, 0, stream>>>(H, attf, attb, SC);
  k_mlp<<<NB/8, 256, 0, stream>>>(H, w1f_m, mb1, mw2, PART);
  k_final<<<NB/256, 256, 0, stream>>>(SC, PART, mb2, out);
}

// Round 9
// 608.888 us; speedup vs baseline: 1.0636x; 1.0636x over previous
//
#include <hip/hip_runtime.h>

#define NB     16384
#define TEAM   5
#define NPAIR  20
#define UPAIR  10             // unordered pairs: prod/order2 are symmetric in (i,j)
#define PD     256
#define HD     256
#define H1D    512
#define NPLAY  (NB*TEAM)      // 81920
#define NCHUNK 1

typedef __attribute__((ext_vector_type(4))) float f32x4;
typedef __attribute__((ext_vector_type(8))) short s16x8;

__device__ __forceinline__ float silu_f(float x){ return x / (1.0f + __expf(-x)); }

__device__ __forceinline__ unsigned short bf16_rne(float x){
  unsigned u = __float_as_uint(x);
  unsigned r = u + 0x7fffu + ((u >> 16) & 1u);
  return (unsigned short)(r >> 16);
}
__device__ __forceinline__ float bf16_to_f(unsigned short s){
  return __uint_as_float(((unsigned)s) << 16);
}
// truncation split: hi = trunc16(x), lo = trunc16(x - hi). Validated r3-r8
// (absmax 5.96e-8, passes). 4 VALU/elem vs 10 for double-RNE.
__device__ __forceinline__ void tsplit(float x, short& h, short& l){
  const unsigned u = __float_as_uint(x);
  h = (short)(u >> 16);
  const float lf = x - __uint_as_float(u & 0xffff0000u);
  l = (short)(__float_as_uint(lf) >> 16);
}

// ---------------------------------------------------------------------------
// k_pack4 (round-17): all four weight packs fused into ONE dispatch.
// Segments are multiples of 256 -> block-uniform branches. Saves 3 launch
// overheads + 3 tail drains vs 4 serial tiny kernels.
// ---------------------------------------------------------------------------
__global__ void k_pack4(const float* __restrict__ mw1, const float* __restrict__ fw1,
                        const float* __restrict__ fw2, const float* __restrict__ attw,
                        short* __restrict__ w1f_m, short* __restrict__ w1f_f,
                        short* __restrict__ w2f_f, short* __restrict__ attf)
{
  const int tid = blockIdx.x * 256 + threadIdx.x;
  const float* w; short* wf; int KT, total, lt;
  if (tid < 131072)      { w = mw1;  wf = w1f_m; KT = 8;  total = 131072; lt = tid; }
  else if (tid < 262144) { w = fw1;  wf = w1f_f; KT = 8;  total = 131072; lt = tid - 131072; }
  else if (tid < 393216) { w = fw2;  wf = w2f_f; KT = 16; total = 131072; lt = tid - 262144; }
  else                   { w = attw; wf = attf;  KT = 8;  total = 65536;  lt = tid - 393216; }

  const int slot = lt & 7;
  const int lane = (lt >> 3) & 63;
  const int grp  = lt >> 9;
  const int kt   = grp % KT;
  const int nt   = grp / KT;
  const int K    = KT * 32;
  const int n = nt * 16 + (lane & 15);
  const int k = kt * 32 + ((lane >> 4) << 3) + slot;
  const float v = w[(size_t)n * K + k];
  const unsigned short hi = bf16_rne(v);
  const float lo = v - bf16_to_f(hi);
  wf[lt]         = (short)hi;
  wf[total + lt] = (short)bf16_rne(lo);
}

// ---------------------------------------------------------------------------
// k_l1: cy=2 grid, acc[5][4], single-Af 2-barrier lockstep (proven optimum;
// r8's dbuf pipeline cost occupancy and regressed). tsplit staging.
// ---------------------------------------------------------------------------
__global__ __launch_bounds__(256) void k_l1(
    const int* __restrict__ tids, const float* __restrict__ emb,
    const short* __restrict__ w1f, const float* __restrict__ b1,
    float* __restrict__ Hh1)
{
  __shared__ short Af[10240];   // hi at 0, lo at +5120 : 20.5 KB
  __shared__ float Bb[256];
  __shared__ int   Tid[80];

  const int t = threadIdx.x, lane = t & 63, w = t >> 6;
  const int bx = blockIdx.x, cy = blockIdx.y;
  const int p0 = bx * 80;

  if (t < 80) Tid[t] = tids[p0 + t];
  Bb[t] = b1[cy * 256 + t];

  f32x4 acc[5][4];
  #pragma unroll
  for (int mt = 0; mt < 5; ++mt)
    #pragma unroll
    for (int j = 0; j < 4; ++j) acc[mt][j] = (f32x4){0.f,0.f,0.f,0.f};

  const s16x8* Bh = reinterpret_cast<const s16x8*>(w1f);   // hi; lo at +16384 units

  for (int kt = 0; kt < 8; ++kt) {
    const int kc = kt >> 1, ks = kt & 1;
    if (ks == 0) {
      __syncthreads();                  // prev chunk reads done / Tid ready
      const int kt0 = kc * 64;
      #pragma unroll
      for (int f = 0; f < 5; ++f) {
        const int idx4  = t + f * 256;            // 0..1279
        const int sg    = (idx4 & 1) * 4;
        const int lane_ = (idx4 >> 1) & 63;
        const int ks_   = (idx4 >> 7) & 1;
        const int mt_   = idx4 >> 8;              // 0..4
        const int p     = mt_ * 16 + (lane_ & 15);
        const int k     = kt0 + ks_ * 32 + ((lane_ >> 4) << 3) + sg;
        const int row   = Tid[p];
        const float4 a4 = *reinterpret_cast<const float4*>(emb + (size_t)row * PD + k);
        float pv[4] = {a4.x, a4.y, a4.z, a4.w};
        short hi[4], lo[4];
        #pragma unroll
        for (int e = 0; e < 4; ++e) tsplit(pv[e], hi[e], lo[e]);
        const int aoff = (mt_ * 2 + ks_) * 512 + lane_ * 8 + sg;
        *reinterpret_cast<short4*>(&Af[aoff])        = make_short4(hi[0],hi[1],hi[2],hi[3]);
        *reinterpret_cast<short4*>(&Af[5120 + aoff]) = make_short4(lo[0],lo[1],lo[2],lo[3]);
      }
      __syncthreads();
    }

    s16x8 ah[5], al[5];
    #pragma unroll
    for (int mt = 0; mt < 5; ++mt) {
      ah[mt] = *reinterpret_cast<const s16x8*>(&Af[(mt*2 + ks)*512 + lane*8]);
      al[mt] = *reinterpret_cast<const s16x8*>(&Af[5120 + (mt*2 + ks)*512 + lane*8]);
    }
    #pragma unroll
    for (int j = 0; j < 4; ++j) {
      const int nt = cy * 16 + w * 4 + j;
      const s16x8 bh = Bh[(nt*8 + kt)*64 + lane];
      const s16x8 bl = Bh[16384 + (nt*8 + kt)*64 + lane];
      #pragma unroll
      for (int mt = 0; mt < 5; ++mt) {
        acc[mt][j] = __builtin_amdgcn_mfma_f32_16x16x32_bf16(ah[mt], bh, acc[mt][j], 0,0,0);
        acc[mt][j] = __builtin_amdgcn_mfma_f32_16x16x32_bf16(al[mt], bh, acc[mt][j], 0,0,0);
        acc[mt][j] = __builtin_amdgcn_mfma_f32_16x16x32_bf16(ah[mt], bl, acc[mt][j], 0,0,0);
      }
    }
  }

  // epilogue: bias + silu -> Hh1 fp32 C-layout
  #pragma unroll
  for (int mt = 0; mt < 5; ++mt)
    #pragma unroll
    for (int j = 0; j < 4; ++j) {
      const int nl = w * 64 + j * 16 + (lane & 15);
      const int n  = cy * 256 + nl;
      #pragma unroll
      for (int r = 0; r < 4; ++r) {
        const int p = p0 + mt*16 + ((lane >> 4) << 2) + r;
        Hh1[(size_t)p * H1D + n] = silu_f(acc[mt][j][r] + Bb[nl]);
      }
    }
}

// k_l2: h[p][n] = h1[p] @ w2^T + b2, K=512, N=256. Trunc-split staging.
// Single-Af 2-barrier lockstep (r8 dbuf regressed -> reverted).
__global__ __launch_bounds__(256) void k_l2(
    const float* __restrict__ Hh1, const short* __restrict__ w2f,
    const float* __restrict__ b2, float* __restrict__ Hout)
{
  __shared__ short Af[10240];   // 20.5 KB
  __shared__ float Bb[256];

  const int t = threadIdx.x, lane = t & 63, w = t >> 6;
  const int bx = blockIdx.x;
  const int p0 = bx * 80;

  Bb[t] = b2[t];

  const int sg    = (t & 1) * 4;
  const int lane_ = (t >> 1) & 63;
  const int ks_   = (t >> 7) & 1;
  const int kb    = ks_ * 32 + ((lane_ >> 4) << 3) + sg;
  int rowH[5], aof[5];
  #pragma unroll
  for (int f = 0; f < 5; ++f) {
    rowH[f] = (p0 + f * 16 + (lane_ & 15)) * H1D;
    aof[f]  = (f * 2 + ks_) * 512 + lane_ * 8 + sg;
  }

  f32x4 acc[5][4];
  #pragma unroll
  for (int mt = 0; mt < 5; ++mt)
    #pragma unroll
    for (int j = 0; j < 4; ++j) acc[mt][j] = (f32x4){0.f,0.f,0.f,0.f};

  const s16x8* B2 = reinterpret_cast<const s16x8*>(w2f);   // hi; lo at +16384 units

  for (int kt = 0; kt < 16; ++kt) {
    const int kc = kt >> 1, ks = kt & 1;
    if (ks == 0) {
      __syncthreads();
      const int kk = kc * 64 + kb;
      #pragma unroll
      for (int f = 0; f < 5; ++f) {
        const float4 a4 = *reinterpret_cast<const float4*>(Hh1 + rowH[f] + kk);
        float pv[4] = {a4.x, a4.y, a4.z, a4.w};
        short hi[4], lo[4];
        #pragma unroll
        for (int e = 0; e < 4; ++e) tsplit(pv[e], hi[e], lo[e]);
        *reinterpret_cast<short4*>(&Af[aof[f]])        = make_short4(hi[0],hi[1],hi[2],hi[3]);
        *reinterpret_cast<short4*>(&Af[5120 + aof[f]]) = make_short4(lo[0],lo[1],lo[2],lo[3]);
      }
      __syncthreads();
    }

    s16x8 ah[5], al[5];
    #pragma unroll
    for (int mt = 0; mt < 5; ++mt) {
      ah[mt] = *reinterpret_cast<const s16x8*>(&Af[(mt*2 + ks)*512 + lane*8]);
      al[mt] = *reinterpret_cast<const s16x8*>(&Af[5120 + (mt*2 + ks)*512 + lane*8]);
    }
    #pragma unroll
    for (int j = 0; j < 4; ++j) {
      const int nt = w * 4 + j;
      const s16x8 bh = B2[(nt*16 + kt)*64 + lane];
      const s16x8 bl = B2[16384 + (nt*16 + kt)*64 + lane];
      #pragma unroll
      for (int mt = 0; mt < 5; ++mt) {
        acc[mt][j] = __builtin_amdgcn_mfma_f32_16x16x32_bf16(ah[mt], bh, acc[mt][j], 0,0,0);
        acc[mt][j] = __builtin_amdgcn_mfma_f32_16x16x32_bf16(al[mt], bh, acc[mt][j], 0,0,0);
        acc[mt][j] = __builtin_amdgcn_mfma_f32_16x16x32_bf16(ah[mt], bl, acc[mt][j], 0,0,0);
      }
    }
  }

  // epilogue: +b2, C-layout store
  #pragma unroll
  for (int mt = 0; mt < 5; ++mt)
    #pragma unroll
    for (int j = 0; j < 4; ++j) {
      const int n = w * 64 + j * 16 + (lane & 15);
      #pragma unroll
      for (int r = 0; r < 4; ++r) {
        const int p = p0 + mt*16 + ((lane >> 4) << 2) + r;
        Hout[(size_t)p * PD + n] = acc[mt][j][r] + Bb[n];
      }
    }
}

// ---------------------------------------------------------------------------
// Kernel A v4 (FALLBACK when ws too small for the split): unchanged.
// ---------------------------------------------------------------------------
__global__ __launch_bounds__(256) void k_fm4(
    const int* __restrict__ tids, const float* __restrict__ emb,
    const short* __restrict__ w1f, const float* __restrict__ b1,
    const short* __restrict__ w2f, const float* __restrict__ b2,
    float* __restrict__ Hout)
{
  __shared__ char smem[65536 + 3072];
  short* Af  = reinterpret_cast<short*>(smem);
  short* H1f = reinterpret_cast<short*>(smem);
  float* Bb  = reinterpret_cast<float*>(smem + 65536);

  const int t = threadIdx.x, lane = t & 63, w = t >> 6;
  const int m0 = blockIdx.x * 32;

  Bb[t]       = b1[t];
  Bb[t + 256] = b1[t + 256];
  Bb[t + 512] = b2[t];

  #pragma unroll
  for (int f = 0; f < 8; ++f) {
    const int g     = t + f * 256;
    const int sg    = (g & 1) * 4;
    const int lane_ = (g >> 1) & 63;
    const int kt_   = (g >> 7) & 7;
    const int mt_   = g >> 10;
    const int p     = mt_ * 16 + (lane_ & 15);
    const int k     = kt_ * 32 + ((lane_ >> 4) << 3) + sg;
    const int row   = tids[m0 + p];
    const float4 a4 = *reinterpret_cast<const float4*>(emb + (size_t)row * PD + k);
    float pv[4] = {a4.x, a4.y, a4.z, a4.w};
    short hi[4], lo[4];
    #pragma unroll
    for (int e = 0; e < 4; ++e) {
      const unsigned short h = bf16_rne(pv[e]);
      hi[e] = (short)h;
      lo[e] = (short)bf16_rne(pv[e] - bf16_to_f(h));
    }
    const int off = ((mt_*8 + kt_)*64 + lane_)*8 + sg;
    *reinterpret_cast<short4*>(&Af[off])        = make_short4(hi[0],hi[1],hi[2],hi[3]);
    *reinterpret_cast<short4*>(&Af[8192 + off]) = make_short4(lo[0],lo[1],lo[2],lo[3]);
  }
  __syncthreads();

  const s16x8* B1 = reinterpret_cast<const s16x8*>(w1f);
  const s16x8* B2 = reinterpret_cast<const s16x8*>(w2f);

  f32x4 acc1[2][8];
  #pragma unroll
  for (int mt = 0; mt < 2; ++mt)
    #pragma unroll
    for (int j = 0; j < 8; ++j) acc1[mt][j] = (f32x4){0.f,0.f,0.f,0.f};

  #pragma unroll
  for (int kt = 0; kt < 8; ++kt) {
    s16x8 ah[2], al[2];
    #pragma unroll
    for (int mt = 0; mt < 2; ++mt) {
      ah[mt] = *reinterpret_cast<const s16x8*>(&Af[((mt*8 + kt)*64 + lane)*8]);
      al[mt] = *reinterpret_cast<const s16x8*>(&Af[8192 + ((mt*8 + kt)*64 + lane)*8]);
    }
    #pragma unroll
    for (int j = 0; j < 8; ++j) {
      const int nt = w * 8 + j;
      const s16x8 bh = B1[(nt*8 + kt)*64 + lane];
      const s16x8 bl = B1[16384 + (nt*8 + kt)*64 + lane];
      #pragma unroll
      for (int mt = 0; mt < 2; ++mt) {
        acc1[mt][j] = __builtin_amdgcn_mfma_f32_16x16x32_bf16(ah[mt], bh, acc1[mt][j], 0,0,0);
        acc1[mt][j] = __builtin_amdgcn_mfma_f32_16x16x32_bf16(al[mt], bh, acc1[mt][j], 0,0,0);
        acc1[mt][j] = __builtin_amdgcn_mfma_f32_16x16x32_bf16(ah[mt], bl, acc1[mt][j], 0,0,0);
      }
    }
  }
  __syncthreads();

  #pragma unroll
  for (int mt = 0; mt < 2; ++mt)
    #pragma unroll
    for (int j = 0; j < 8; ++j) {
      const int n     = w * 128 + j * 16 + (lane & 15);
      const int kt2   = n >> 5;
      const int lhalf = 16 * ((n >> 3) & 3);
      const int slot2 = n & 7;
      #pragma unroll
      for (int r = 0; r < 4; ++r) {
        const int prow = ((lane >> 4) << 2) + r;
        const float v = silu_f(acc1[mt][j][r] + Bb[n]);
        const unsigned short hi = bf16_rne(v);
        const int off = ((mt*16 + kt2)*64 + lhalf + prow)*8 + slot2;
        H1f[off]         = (short)hi;
        H1f[16384 + off] = (short)bf16_rne(v - bf16_to_f(hi));
      }
    }
  __syncthreads();

  f32x4 acc2[2][4];
  #pragma unroll
  for (int mt = 0; mt < 2; ++mt)
    #pragma unroll
    for (int j = 0; j < 4; ++j) acc2[mt][j] = (f32x4){0.f,0.f,0.f,0.f};

  #pragma unroll
  for (int kt = 0; kt < 16; ++kt) {
    s16x8 ah[2], al[2];
    #pragma unroll
    for (int mt = 0; mt < 2; ++mt) {
      ah[mt] = *reinterpret_cast<const s16x8*>(&H1f[((mt*16 + kt)*64 + lane)*8]);
      al[mt] = *reinterpret_cast<const s16x8*>(&H1f[16384 + ((mt*16 + kt)*64 + lane)*8]);
    }
    #pragma unroll
    for (int j = 0; j < 4; ++j) {
      const int nt = w * 4 + j;
      const s16x8 bh = B2[(nt*16 + kt)*64 + lane];
      const s16x8 bl = B2[16384 + (nt*16 + kt)*64 + lane];
      #pragma unroll
      for (int mt = 0; mt < 2; ++mt) {
        acc2[mt][j] = __builtin_amdgcn_mfma_f32_16x16x32_bf16(ah[mt], bh, acc2[mt][j], 0,0,0);
        acc2[mt][j] = __builtin_amdgcn_mfma_f32_16x16x32_bf16(al[mt], bh, acc2[mt][j], 0,0,0);
        acc2[mt][j] = __builtin_amdgcn_mfma_f32_16x16x32_bf16(ah[mt], bl, acc2[mt][j], 0,0,0);
      }
    }
  }

  #pragma unroll
  for (int mt = 0; mt < 2; ++mt)
    #pragma unroll
    for (int j = 0; j < 4; ++j) {
      const int n = w * 64 + j * 16 + (lane & 15);
      #pragma unroll
      for (int r = 0; r < 4; ++r) {
        const int p = m0 + mt*16 + ((lane >> 4) << 2) + r;
        Hout[(size_t)p * PD + n] = acc2[mt][j][r] + Bb[512 + n];
      }
    }
}

// ---------------------------------------------------------------------------
// Kernel B v3.2: att+score; trunc-split staging. (602 build, unchanged)
// ---------------------------------------------------------------------------
__global__ __launch_bounds__(256) void k_score(
    const float* __restrict__ Hin, const short* __restrict__ attf,
    const float* __restrict__ attb, float* __restrict__ SC)
{
  __shared__ char smem[49152 + 1024];
  short* Hf  = reinterpret_cast<short*>(smem);
  float* WAl = reinterpret_cast<float*>(smem);
  float* Ab  = reinterpret_cast<float*>(smem + 49152);

  const int t = threadIdx.x, lane = t & 63, w = t >> 6;
  const int b0 = blockIdx.x * 8;
  const float* src = Hin + (size_t)b0 * TEAM * PD;

  Ab[t] = attb[t];

  #pragma unroll
  for (int f = 0; f < 12; ++f) {
    const int g     = t + f * 256;
    const int sg    = (g & 1) * 4;
    const int lane_ = (g >> 1) & 63;
    const int kt_   = (g >> 7) & 7;
    const int mt_   = g >> 10;
    const int p     = mt_ * 16 + (lane_ & 15);
    const int k     = kt_ * 32 + ((lane_ >> 4) << 3) + sg;
    float4 a4 = make_float4(0.f, 0.f, 0.f, 0.f);
    if (p < 40) a4 = *reinterpret_cast<const float4*>(src + (size_t)p * PD + k);
    float pv[4] = {a4.x, a4.y, a4.z, a4.w};
    short hi[4], lo[4];
    #pragma unroll
    for (int e = 0; e < 4; ++e) tsplit(pv[e], hi[e], lo[e]);
    const int off = ((mt_*8 + kt_)*64 + lane_)*8 + sg;
    *reinterpret_cast<short4*>(&Hf[off])         = make_short4(hi[0],hi[1],hi[2],hi[3]);
    *reinterpret_cast<short4*>(&Hf[12288 + off]) = make_short4(lo[0],lo[1],lo[2],lo[3]);
  }
  __syncthreads();

  f32x4 acc[3][4];
  #pragma unroll
  for (int mt = 0; mt < 3; ++mt)
    #pragma unroll
    for (int j = 0; j < 4; ++j) acc[mt][j] = (f32x4){0.f,0.f,0.f,0.f};

  const s16x8* Bh = reinterpret_cast<const s16x8*>(attf);
  #pragma unroll
  for (int kt = 0; kt < 8; ++kt) {
    s16x8 ah[3], al[3];
    #pragma unroll
    for (int mt = 0; mt < 3; ++mt) {
      ah[mt] = *reinterpret_cast<const s16x8*>(&Hf[((mt*8 + kt)*64 + lane)*8]);
      al[mt] = *reinterpret_cast<const s16x8*>(&Hf[12288 + ((mt*8 + kt)*64 + lane)*8]);
    }
    #pragma unroll
    for (int j = 0; j < 4; ++j) {
      const int nt = w * 4 + j;
      const s16x8 bh = Bh[(nt*8 + kt)*64 + lane];
      const s16x8 bl = Bh[8192 + (nt*8 + kt)*64 + lane];
      #pragma unroll
      for (int mt = 0; mt < 3; ++mt) {
        acc[mt][j] = __builtin_amdgcn_mfma_f32_16x16x32_bf16(ah[mt], bh, acc[mt][j], 0,0,0);
        acc[mt][j] = __builtin_amdgcn_mfma_f32_16x16x32_bf16(al[mt], bh, acc[mt][j], 0,0,0);
        acc[mt][j] = __builtin_amdgcn_mfma_f32_16x16x32_bf16(ah[mt], bl, acc[mt][j], 0,0,0);
      }
    }
  }
  __syncthreads();

  #pragma unroll
  for (int mt = 0; mt < 3; ++mt)
    #pragma unroll
    for (int j = 0; j < 4; ++j) {
      const int n = w * 64 + j * 16 + (lane & 15);
      #pragma unroll
      for (int r = 0; r < 4; ++r) {
        const int row = mt * 16 + ((lane >> 4) << 2) + r;
        if (row < 40) WAl[row * 260 + n] = acc[mt][j][r] + Ab[n];
      }
    }
  __syncthreads();

  #pragma unroll
  for (int qq = 0; qq < 2; ++qq) {
    const int q = w * 2 + qq;
    #pragma unroll
    for (int p = 0; p < NPAIR; ++p) {
      const int i1 = p >> 2, jj = p & 3;
      const int i2 = jj + (jj >= i1 ? 1 : 0);
      const float4 a4 = *reinterpret_cast<const float4*>(WAl + (q*TEAM + i1) * 260 + lane * 4);
      const float4 b4 = *reinterpret_cast<const float4*>(src + (size_t)(q*TEAM + i2) * PD + lane * 4);
      float v = a4.x*b4.x + a4.y*b4.y + a4.z*b4.z + a4.w*b4.w;
      #pragma unroll
      for (int off = 32; off > 0; off >>= 1) v += __shfl_xor(v, off);
      if (lane == 0) SC[(size_t)(b0 + q) * NPAIR + p] = v;
    }
  }
}

// ---------------------------------------------------------------------------
// Kernel C: pair MLP -- 602-build form (189 us, MfmaUtil 30%). Reg-bound
// 2-block lockstep; r4/r8 proved pipelining variants spill or lose occupancy.
// ---------------------------------------------------------------------------
__global__ __launch_bounds__(256, 2) void k_mlp(
    const float* __restrict__ Hin, const short* __restrict__ w1f,
    const float* __restrict__ b1, const float* __restrict__ w2,
    float* __restrict__ PART)
{
  __shared__ float Hl[40*260];      // 41.6 KB
  __shared__ short Af[10240];       // 20.5 KB (hi at 0, lo at +5120)
  __shared__ float Wb[512];
  __shared__ float Ww[512];

  const int t    = threadIdx.x;
  const int lane = t & 63;
  const int w    = t >> 6;
  const int blkx = blockIdx.x;
  const int b0   = blkx * 8;
  const float* src = Hin + (size_t)b0 * TEAM * PD;

  {
    #pragma unroll
    for (int rep = 0; rep < 10; ++rep) {
      const int flat = t + rep * 256;
      const int row = flat >> 6, c4 = (flat & 63) * 4;
      *reinterpret_cast<float4*>(Hl + row * 260 + c4) =
        *reinterpret_cast<const float4*>(src + (size_t)row * PD + c4);
    }
    Wb[t]       = b1[t];
    Wb[t + 256] = b1[t + 256];
    Ww[t]       = w2[t];
    Ww[t + 256] = w2[t + 256];
  }

  // hoisted staging geometry (invariant per thread; mt_ == f)
  const int sg    = (t & 1) * 4;
  const int lane_ = (t >> 1) & 63;
  const int ks_   = (t >> 7) & 1;
  const int kb    = ks_ * 32 + ((lane_ >> 4) << 3) + sg;
  int rowA[5], rowB[5], aof[5];
  #pragma unroll
  for (int f = 0; f < 5; ++f) {
    const int r  = f * 16 + (lane_ & 15);       // pair-row 0..79
    const int q  = r / UPAIR;
    const int p  = r - q * UPAIR;
    const int i1 = (p >= 4) + (p >= 7) + (p >= 9);
    const int i2 = p - (i1 * (9 - i1)) / 2 + i1 + 1;
    rowA[f] = (q * TEAM + i1) * 260;
    rowB[f] = (q * TEAM + i2) * 260;
    aof[f]  = (f * 2 + ks_) * 512 + lane_ * 8 + sg;
  }

  f32x4 acc[5][8];
  #pragma unroll
  for (int mt = 0; mt < 5; ++mt)
    #pragma unroll
    for (int j = 0; j < 8; ++j) acc[mt][j] = (f32x4){0.f,0.f,0.f,0.f};

  const s16x8* Bh = reinterpret_cast<const s16x8*>(w1f);
  const s16x8* Bl = reinterpret_cast<const s16x8*>(w1f + 131072);
  const int nt0 = w * 8;

  for (int kt = 0; kt < 8; ++kt) {
    const int kc = kt >> 1, ks = kt & 1;
    if (ks == 0) {
      __syncthreads();              // Hl fill done (kt=0) / prev chunk reads done
      const int kk = kc * 64 + kb;
      #pragma unroll
      for (int f = 0; f < 5; ++f) {
        const float4 a4 = *reinterpret_cast<const float4*>(Hl + rowA[f] + kk);
        const float4 b4 = *reinterpret_cast<const float4*>(Hl + rowB[f] + kk);
        float pv[4] = {a4.x*b4.x, a4.y*b4.y, a4.z*b4.z, a4.w*b4.w};
        short hi[4], lo[4];
        #pragma unroll
        for (int e = 0; e < 4; ++e) tsplit(pv[e], hi[e], lo[e]);
        *reinterpret_cast<short4*>(&Af[aof[f]])        = make_short4(hi[0],hi[1],hi[2],hi[3]);
        *reinterpret_cast<short4*>(&Af[5120 + aof[f]]) = make_short4(lo[0],lo[1],lo[2],lo[3]);
      }
      __syncthreads();
    }

    s16x8 ah[5], al[5];
    #pragma unroll
    for (int mt = 0; mt < 5; ++mt) {
      ah[mt] = *reinterpret_cast<const s16x8*>(&Af[(mt*2 + ks)*512 + lane*8]);
      al[mt] = *reinterpret_cast<const s16x8*>(&Af[5120 + (mt*2 + ks)*512 + lane*8]);
    }
    #pragma unroll
    for (int j = 0; j < 8; ++j) {
      const s16x8 bh = Bh[((nt0 + j)*8 + kt)*64 + lane];
      const s16x8 bl = Bl[((nt0 + j)*8 + kt)*64 + lane];
      #pragma unroll
      for (int mt = 0; mt < 5; ++mt) {
        acc[mt][j] = __builtin_amdgcn_mfma_f32_16x16x32_bf16(ah[mt], bh, acc[mt][j], 0,0,0);
        acc[mt][j] = __builtin_amdgcn_mfma_f32_16x16x32_bf16(ah[mt], bl, acc[mt][j], 0,0,0);
        acc[mt][j] = __builtin_amdgcn_mfma_f32_16x16x32_bf16(al[mt], bh, acc[mt][j], 0,0,0);
      }
    }
  }

  __syncthreads();
  float* red = reinterpret_cast<float*>(Af);

  const int colbase = w * 128 + (lane & 15);
  #pragma unroll
  for (int mt = 0; mt < 5; ++mt)
    #pragma unroll
    for (int r = 0; r < 4; ++r) {
      float s = 0.0f;
      #pragma unroll
      for (int j = 0; j < 8; ++j) {
        const int c = colbase + j * 16;
        s += silu_f(acc[mt][j][r] + Wb[c]) * Ww[c];
      }
      s += __shfl_xor(s, 1); s += __shfl_xor(s, 2);
      s += __shfl_xor(s, 4); s += __shfl_xor(s, 8);
      if ((lane & 15) == 0) {
        const int row = mt * 16 + ((lane >> 4) << 2) + r;
        red[row * 4 + w] = s;
      }
    }
  __syncthreads();
  if (t < 80) {
    const float s = red[t*4] + red[t*4+1] + red[t*4+2] + red[t*4+3];
    PART[(size_t)blkx * 80 + t] = s;
  }
}

// ---------------------------------------------------------------------------
// Kernel D: one thread per batch.
// ---------------------------------------------------------------------------
__global__ void k_final(const float* __restrict__ SC, const float* __restrict__ PART,
                        const float* __restrict__ mb2, float* __restrict__ out)
{
  const int b = blockIdx.x * 256 + threadIdx.x;
  if (b >= NB) return;
  const float bias2 = mb2[0];
  float ord[UPAIR];
  #pragma unroll
  for (int u = 0; u < UPAIR; ++u) {
    float s = bias2;
    #pragma unroll
    for (int g = 0; g < NCHUNK; ++g) s += PART[(size_t)g * (NB*UPAIR) + (size_t)b * UPAIR + u];
    ord[u] = s;
  }
  float sc[NPAIR];
  #pragma unroll
  for (int p = 0; p < NPAIR; ++p) sc[p] = SC[(size_t)b * NPAIR + p];

  float res = 0.0f;
  #pragma unroll
  for (int i = 0; i < TEAM; ++i) {
    float m = sc[4*i];
    #pragma unroll
    for (int jj = 1; jj < 4; ++jj) m = fmaxf(m, sc[4*i + jj]);
    float e[4], d = 0.0f;
    #pragma unroll
    for (int jj = 0; jj < 4; ++jj) { e[jj] = __expf(sc[4*i + jj] - m); d += e[jj]; }
    const float inv = 1.0f / d;
    #pragma unroll
    for (int jj = 0; jj < 4; ++jj) {
      const int i2 = jj + (jj >= i ? 1 : 0);
      const int a  = i < i2 ? i : i2;
      const int bb = i < i2 ? i2 : i;
      const int u  = (a * (9 - a)) / 2 + (bb - a - 1);
      res += ord[u] * e[jj] * inv;
    }
  }
  out[b] = res;
}

// ---------------------------------------------------------------------------
extern "C" void kernel_launch(void* const* d_in, const int* in_sizes, int n_in,
                              void* d_out, int out_size, void* d_ws, size_t ws_size,
                              hipStream_t stream)
{
  (void)in_sizes; (void)n_in; (void)out_size;
  const int*   tids = (const int*)  d_in[0];
  const float* emb  = (const float*)d_in[1];
  const float* fw1  = (const float*)d_in[2];
  const float* fb1  = (const float*)d_in[3];
  const float* fw2  = (const float*)d_in[4];
  const float* fb2  = (const float*)d_in[5];
  const float* attw = (const float*)d_in[6];
  const float* attb = (const float*)d_in[7];
  const float* mw1  = (const float*)d_in[8];
  const float* mb1  = (const float*)d_in[9];
  const float* mw2  = (const float*)d_in[10];
  const float* mb2  = (const float*)d_in[11];
  float* out = (float*)d_out;

  float* H     = (float*)d_ws;                        // 81920*256 f32 = 84 MB
  float* SC    = H + (size_t)NPLAY * PD;              // NB*20 f32
  float* PART  = SC + (size_t)NB * NPAIR;             // NCHUNK*NB*10 f32
  short* w1f_m = (short*)(PART + (size_t)NCHUNK * NB * UPAIR); // mlp_w1 packed
  short* w1f_f = w1f_m + 262144;                      // fm_w1 packed
  short* w2f_f = w1f_f + 262144;                      // fm_w2 packed
  short* attf  = w2f_f + 262144;                      // att_w packed
  float* Hh1   = (float*)(attf + 131072);             // 81920*512 f32 = 168 MB
  const size_t NEED = (size_t)((char*)(Hh1 + (size_t)NPLAY * H1D) - (char*)d_ws);

  k_pack4<<<1792, 256, 0, stream>>>(mw1, fw1, fw2, attw, w1f_m, w1f_f, w2f_f, attf);

  if (ws_size >= NEED) {
    k_l1<<<dim3(NPLAY/80, 2), 256, 0, stream>>>(tids, emb, w1f_f, fb1, Hh1);
    k_l2<<<NPLAY/80, 256, 0, stream>>>(Hh1, w2f_f, fb2, H);
  } else {
    k_fm4<<<NPLAY/32, 256, 0, stream>>>(tids, emb, w1f_f, fb1, w2f_f, fb2, H);
  }
  k_score<<<NB/8, 256, 0, stream>>>(H, attf, attb, SC);
  k_mlp<<<NB/8, 256, 0, stream>>>(H, w1f_m, mb1, mw2, PART);
  k_final<<<NB/256, 256, 0, stream>>>(SC, PART, mb2, out);
}

// Round 10
// 598.691 us; speedup vs baseline: 1.0817x; 1.0170x over previous
//
#include <hip/hip_runtime.h>

#define NB     16384
#define TEAM   5
#define NPAIR  20
#define UPAIR  10             // unordered pairs: prod/order2 are symmetric in (i,j)
#define PD     256
#define HD     256
#define H1D    512
#define NPLAY  (NB*TEAM)      // 81920
#define NCHUNK 2              // k_mlp column chunks (round-10: the untested middle)

typedef __attribute__((ext_vector_type(4))) float f32x4;
typedef __attribute__((ext_vector_type(8))) short s16x8;

__device__ __forceinline__ float silu_f(float x){ return x / (1.0f + __expf(-x)); }

__device__ __forceinline__ unsigned short bf16_rne(float x){
  unsigned u = __float_as_uint(x);
  unsigned r = u + 0x7fffu + ((u >> 16) & 1u);
  return (unsigned short)(r >> 16);
}
__device__ __forceinline__ float bf16_to_f(unsigned short s){
  return __uint_as_float(((unsigned)s) << 16);
}
// truncation split: hi = trunc16(x), lo = trunc16(x - hi). Validated r3-r9
// (absmax 5.96e-8, passes). 4 VALU/elem vs 10 for double-RNE.
__device__ __forceinline__ void tsplit(float x, short& h, short& l){
  const unsigned u = __float_as_uint(x);
  h = (short)(u >> 16);
  const float lf = x - __uint_as_float(u & 0xffff0000u);
  l = (short)(__float_as_uint(lf) >> 16);
}

// ---------------------------------------------------------------------------
// Generic prep: pack an N x K fp32 row-major matrix into MFMA B-fragment
// order, split bf16 hi/lo. (r7-exact: 4 separate launches; r9's fusion was
// neutral-to-negative.)
// ---------------------------------------------------------------------------
__global__ void k_pack(const float* __restrict__ w, short* __restrict__ wf,
                       int KT, int total)
{
  const int tid = blockIdx.x * 256 + threadIdx.x;
  if (tid >= total) return;
  const int slot = tid & 7;
  const int lane = (tid >> 3) & 63;
  const int grp  = tid >> 9;
  const int kt   = grp % KT;
  const int nt   = grp / KT;
  const int K    = KT * 32;
  const int n = nt * 16 + (lane & 15);
  const int k = kt * 32 + ((lane >> 4) << 3) + slot;
  const float v = w[(size_t)n * K + k];
  const unsigned short hi = bf16_rne(v);
  const float lo = v - bf16_to_f(hi);
  wf[tid]         = (short)hi;
  wf[total + tid] = (short)bf16_rne(lo);
}

// ---------------------------------------------------------------------------
// k_l1: cy=2 grid, acc[5][4], single-Af 2-barrier lockstep (proven optimum).
// tsplit staging. (r7-exact)
// ---------------------------------------------------------------------------
__global__ __launch_bounds__(256) void k_l1(
    const int* __restrict__ tids, const float* __restrict__ emb,
    const short* __restrict__ w1f, const float* __restrict__ b1,
    float* __restrict__ Hh1)
{
  __shared__ short Af[10240];   // hi at 0, lo at +5120 : 20.5 KB
  __shared__ float Bb[256];
  __shared__ int   Tid[80];

  const int t = threadIdx.x, lane = t & 63, w = t >> 6;
  const int bx = blockIdx.x, cy = blockIdx.y;
  const int p0 = bx * 80;

  if (t < 80) Tid[t] = tids[p0 + t];
  Bb[t] = b1[cy * 256 + t];

  f32x4 acc[5][4];
  #pragma unroll
  for (int mt = 0; mt < 5; ++mt)
    #pragma unroll
    for (int j = 0; j < 4; ++j) acc[mt][j] = (f32x4){0.f,0.f,0.f,0.f};

  const s16x8* Bh = reinterpret_cast<const s16x8*>(w1f);   // hi; lo at +16384 units

  for (int kt = 0; kt < 8; ++kt) {
    const int kc = kt >> 1, ks = kt & 1;
    if (ks == 0) {
      __syncthreads();                  // prev chunk reads done / Tid ready
      const int kt0 = kc * 64;
      #pragma unroll
      for (int f = 0; f < 5; ++f) {
        const int idx4  = t + f * 256;            // 0..1279
        const int sg    = (idx4 & 1) * 4;
        const int lane_ = (idx4 >> 1) & 63;
        const int ks_   = (idx4 >> 7) & 1;
        const int mt_   = idx4 >> 8;              // 0..4
        const int p     = mt_ * 16 + (lane_ & 15);
        const int k     = kt0 + ks_ * 32 + ((lane_ >> 4) << 3) + sg;
        const int row   = Tid[p];
        const float4 a4 = *reinterpret_cast<const float4*>(emb + (size_t)row * PD + k);
        float pv[4] = {a4.x, a4.y, a4.z, a4.w};
        short hi[4], lo[4];
        #pragma unroll
        for (int e = 0; e < 4; ++e) tsplit(pv[e], hi[e], lo[e]);
        const int aoff = (mt_ * 2 + ks_) * 512 + lane_ * 8 + sg;
        *reinterpret_cast<short4*>(&Af[aoff])        = make_short4(hi[0],hi[1],hi[2],hi[3]);
        *reinterpret_cast<short4*>(&Af[5120 + aoff]) = make_short4(lo[0],lo[1],lo[2],lo[3]);
      }
      __syncthreads();
    }

    s16x8 ah[5], al[5];
    #pragma unroll
    for (int mt = 0; mt < 5; ++mt) {
      ah[mt] = *reinterpret_cast<const s16x8*>(&Af[(mt*2 + ks)*512 + lane*8]);
      al[mt] = *reinterpret_cast<const s16x8*>(&Af[5120 + (mt*2 + ks)*512 + lane*8]);
    }
    #pragma unroll
    for (int j = 0; j < 4; ++j) {
      const int nt = cy * 16 + w * 4 + j;
      const s16x8 bh = Bh[(nt*8 + kt)*64 + lane];
      const s16x8 bl = Bh[16384 + (nt*8 + kt)*64 + lane];
      #pragma unroll
      for (int mt = 0; mt < 5; ++mt) {
        acc[mt][j] = __builtin_amdgcn_mfma_f32_16x16x32_bf16(ah[mt], bh, acc[mt][j], 0,0,0);
        acc[mt][j] = __builtin_amdgcn_mfma_f32_16x16x32_bf16(al[mt], bh, acc[mt][j], 0,0,0);
        acc[mt][j] = __builtin_amdgcn_mfma_f32_16x16x32_bf16(ah[mt], bl, acc[mt][j], 0,0,0);
      }
    }
  }

  // epilogue: bias + silu -> Hh1 fp32 C-layout
  #pragma unroll
  for (int mt = 0; mt < 5; ++mt)
    #pragma unroll
    for (int j = 0; j < 4; ++j) {
      const int nl = w * 64 + j * 16 + (lane & 15);
      const int n  = cy * 256 + nl;
      #pragma unroll
      for (int r = 0; r < 4; ++r) {
        const int p = p0 + mt*16 + ((lane >> 4) << 2) + r;
        Hh1[(size_t)p * H1D + n] = silu_f(acc[mt][j][r] + Bb[nl]);
      }
    }
}

// k_l2: h[p][n] = h1[p] @ w2^T + b2, K=512, N=256. (r7-exact)
__global__ __launch_bounds__(256) void k_l2(
    const float* __restrict__ Hh1, const short* __restrict__ w2f,
    const float* __restrict__ b2, float* __restrict__ Hout)
{
  __shared__ short Af[10240];   // 20.5 KB
  __shared__ float Bb[256];

  const int t = threadIdx.x, lane = t & 63, w = t >> 6;
  const int bx = blockIdx.x;
  const int p0 = bx * 80;

  Bb[t] = b2[t];

  const int sg    = (t & 1) * 4;
  const int lane_ = (t >> 1) & 63;
  const int ks_   = (t >> 7) & 1;
  const int kb    = ks_ * 32 + ((lane_ >> 4) << 3) + sg;
  int rowH[5], aof[5];
  #pragma unroll
  for (int f = 0; f < 5; ++f) {
    rowH[f] = (p0 + f * 16 + (lane_ & 15)) * H1D;
    aof[f]  = (f * 2 + ks_) * 512 + lane_ * 8 + sg;
  }

  f32x4 acc[5][4];
  #pragma unroll
  for (int mt = 0; mt < 5; ++mt)
    #pragma unroll
    for (int j = 0; j < 4; ++j) acc[mt][j] = (f32x4){0.f,0.f,0.f,0.f};

  const s16x8* B2 = reinterpret_cast<const s16x8*>(w2f);   // hi; lo at +16384 units

  for (int kt = 0; kt < 16; ++kt) {
    const int kc = kt >> 1, ks = kt & 1;
    if (ks == 0) {
      __syncthreads();
      const int kk = kc * 64 + kb;
      #pragma unroll
      for (int f = 0; f < 5; ++f) {
        const float4 a4 = *reinterpret_cast<const float4*>(Hh1 + rowH[f] + kk);
        float pv[4] = {a4.x, a4.y, a4.z, a4.w};
        short hi[4], lo[4];
        #pragma unroll
        for (int e = 0; e < 4; ++e) tsplit(pv[e], hi[e], lo[e]);
        *reinterpret_cast<short4*>(&Af[aof[f]])        = make_short4(hi[0],hi[1],hi[2],hi[3]);
        *reinterpret_cast<short4*>(&Af[5120 + aof[f]]) = make_short4(lo[0],lo[1],lo[2],lo[3]);
      }
      __syncthreads();
    }

    s16x8 ah[5], al[5];
    #pragma unroll
    for (int mt = 0; mt < 5; ++mt) {
      ah[mt] = *reinterpret_cast<const s16x8*>(&Af[(mt*2 + ks)*512 + lane*8]);
      al[mt] = *reinterpret_cast<const s16x8*>(&Af[5120 + (mt*2 + ks)*512 + lane*8]);
    }
    #pragma unroll
    for (int j = 0; j < 4; ++j) {
      const int nt = w * 4 + j;
      const s16x8 bh = B2[(nt*16 + kt)*64 + lane];
      const s16x8 bl = B2[16384 + (nt*16 + kt)*64 + lane];
      #pragma unroll
      for (int mt = 0; mt < 5; ++mt) {
        acc[mt][j] = __builtin_amdgcn_mfma_f32_16x16x32_bf16(ah[mt], bh, acc[mt][j], 0,0,0);
        acc[mt][j] = __builtin_amdgcn_mfma_f32_16x16x32_bf16(al[mt], bh, acc[mt][j], 0,0,0);
        acc[mt][j] = __builtin_amdgcn_mfma_f32_16x16x32_bf16(ah[mt], bl, acc[mt][j], 0,0,0);
      }
    }
  }

  // epilogue: +b2, C-layout store
  #pragma unroll
  for (int mt = 0; mt < 5; ++mt)
    #pragma unroll
    for (int j = 0; j < 4; ++j) {
      const int n = w * 64 + j * 16 + (lane & 15);
      #pragma unroll
      for (int r = 0; r < 4; ++r) {
        const int p = p0 + mt*16 + ((lane >> 4) << 2) + r;
        Hout[(size_t)p * PD + n] = acc[mt][j][r] + Bb[n];
      }
    }
}

// ---------------------------------------------------------------------------
// Kernel A v4 (FALLBACK when ws too small for the split): unchanged.
// ---------------------------------------------------------------------------
__global__ __launch_bounds__(256) void k_fm4(
    const int* __restrict__ tids, const float* __restrict__ emb,
    const short* __restrict__ w1f, const float* __restrict__ b1,
    const short* __restrict__ w2f, const float* __restrict__ b2,
    float* __restrict__ Hout)
{
  __shared__ char smem[65536 + 3072];
  short* Af  = reinterpret_cast<short*>(smem);
  short* H1f = reinterpret_cast<short*>(smem);
  float* Bb  = reinterpret_cast<float*>(smem + 65536);

  const int t = threadIdx.x, lane = t & 63, w = t >> 6;
  const int m0 = blockIdx.x * 32;

  Bb[t]       = b1[t];
  Bb[t + 256] = b1[t + 256];
  Bb[t + 512] = b2[t];

  #pragma unroll
  for (int f = 0; f < 8; ++f) {
    const int g     = t + f * 256;
    const int sg    = (g & 1) * 4;
    const int lane_ = (g >> 1) & 63;
    const int kt_   = (g >> 7) & 7;
    const int mt_   = g >> 10;
    const int p     = mt_ * 16 + (lane_ & 15);
    const int k     = kt_ * 32 + ((lane_ >> 4) << 3) + sg;
    const int row   = tids[m0 + p];
    const float4 a4 = *reinterpret_cast<const float4*>(emb + (size_t)row * PD + k);
    float pv[4] = {a4.x, a4.y, a4.z, a4.w};
    short hi[4], lo[4];
    #pragma unroll
    for (int e = 0; e < 4; ++e) {
      const unsigned short h = bf16_rne(pv[e]);
      hi[e] = (short)h;
      lo[e] = (short)bf16_rne(pv[e] - bf16_to_f(h));
    }
    const int off = ((mt_*8 + kt_)*64 + lane_)*8 + sg;
    *reinterpret_cast<short4*>(&Af[off])        = make_short4(hi[0],hi[1],hi[2],hi[3]);
    *reinterpret_cast<short4*>(&Af[8192 + off]) = make_short4(lo[0],lo[1],lo[2],lo[3]);
  }
  __syncthreads();

  const s16x8* B1 = reinterpret_cast<const s16x8*>(w1f);
  const s16x8* B2 = reinterpret_cast<const s16x8*>(w2f);

  f32x4 acc1[2][8];
  #pragma unroll
  for (int mt = 0; mt < 2; ++mt)
    #pragma unroll
    for (int j = 0; j < 8; ++j) acc1[mt][j] = (f32x4){0.f,0.f,0.f,0.f};

  #pragma unroll
  for (int kt = 0; kt < 8; ++kt) {
    s16x8 ah[2], al[2];
    #pragma unroll
    for (int mt = 0; mt < 2; ++mt) {
      ah[mt] = *reinterpret_cast<const s16x8*>(&Af[((mt*8 + kt)*64 + lane)*8]);
      al[mt] = *reinterpret_cast<const s16x8*>(&Af[8192 + ((mt*8 + kt)*64 + lane)*8]);
    }
    #pragma unroll
    for (int j = 0; j < 8; ++j) {
      const int nt = w * 8 + j;
      const s16x8 bh = B1[(nt*8 + kt)*64 + lane];
      const s16x8 bl = B1[16384 + (nt*8 + kt)*64 + lane];
      #pragma unroll
      for (int mt = 0; mt < 2; ++mt) {
        acc1[mt][j] = __builtin_amdgcn_mfma_f32_16x16x32_bf16(ah[mt], bh, acc1[mt][j], 0,0,0);
        acc1[mt][j] = __builtin_amdgcn_mfma_f32_16x16x32_bf16(al[mt], bh, acc1[mt][j], 0,0,0);
        acc1[mt][j] = __builtin_amdgcn_mfma_f32_16x16x32_bf16(ah[mt], bl, acc1[mt][j], 0,0,0);
      }
    }
  }
  __syncthreads();

  #pragma unroll
  for (int mt = 0; mt < 2; ++mt)
    #pragma unroll
    for (int j = 0; j < 8; ++j) {
      const int n     = w * 128 + j * 16 + (lane & 15);
      const int kt2   = n >> 5;
      const int lhalf = 16 * ((n >> 3) & 3);
      const int slot2 = n & 7;
      #pragma unroll
      for (int r = 0; r < 4; ++r) {
        const int prow = ((lane >> 4) << 2) + r;
        const float v = silu_f(acc1[mt][j][r] + Bb[n]);
        const unsigned short hi = bf16_rne(v);
        const int off = ((mt*16 + kt2)*64 + lhalf + prow)*8 + slot2;
        H1f[off]         = (short)hi;
        H1f[16384 + off] = (short)bf16_rne(v - bf16_to_f(hi));
      }
    }
  __syncthreads();

  f32x4 acc2[2][4];
  #pragma unroll
  for (int mt = 0; mt < 2; ++mt)
    #pragma unroll
    for (int j = 0; j < 4; ++j) acc2[mt][j] = (f32x4){0.f,0.f,0.f,0.f};

  #pragma unroll
  for (int kt = 0; kt < 16; ++kt) {
    s16x8 ah[2], al[2];
    #pragma unroll
    for (int mt = 0; mt < 2; ++mt) {
      ah[mt] = *reinterpret_cast<const s16x8*>(&H1f[((mt*16 + kt)*64 + lane)*8]);
      al[mt] = *reinterpret_cast<const s16x8*>(&H1f[16384 + ((mt*16 + kt)*64 + lane)*8]);
    }
    #pragma unroll
    for (int j = 0; j < 4; ++j) {
      const int nt = w * 4 + j;
      const s16x8 bh = B2[(nt*16 + kt)*64 + lane];
      const s16x8 bl = B2[16384 + (nt*16 + kt)*64 + lane];
      #pragma unroll
      for (int mt = 0; mt < 2; ++mt) {
        acc2[mt][j] = __builtin_amdgcn_mfma_f32_16x16x32_bf16(ah[mt], bh, acc2[mt][j], 0,0,0);
        acc2[mt][j] = __builtin_amdgcn_mfma_f32_16x16x32_bf16(al[mt], bh, acc2[mt][j], 0,0,0);
        acc2[mt][j] = __builtin_amdgcn_mfma_f32_16x16x32_bf16(ah[mt], bl, acc2[mt][j], 0,0,0);
      }
    }
  }

  #pragma unroll
  for (int mt = 0; mt < 2; ++mt)
    #pragma unroll
    for (int j = 0; j < 4; ++j) {
      const int n = w * 64 + j * 16 + (lane & 15);
      #pragma unroll
      for (int r = 0; r < 4; ++r) {
        const int p = m0 + mt*16 + ((lane >> 4) << 2) + r;
        Hout[(size_t)p * PD + n] = acc2[mt][j][r] + Bb[512 + n];
      }
    }
}

// ---------------------------------------------------------------------------
// Kernel B v3.2: att+score; trunc-split staging. (r7-exact)
// ---------------------------------------------------------------------------
__global__ __launch_bounds__(256) void k_score(
    const float* __restrict__ Hin, const short* __restrict__ attf,
    const float* __restrict__ attb, float* __restrict__ SC)
{
  __shared__ char smem[49152 + 1024];
  short* Hf  = reinterpret_cast<short*>(smem);
  float* WAl = reinterpret_cast<float*>(smem);
  float* Ab  = reinterpret_cast<float*>(smem + 49152);

  const int t = threadIdx.x, lane = t & 63, w = t >> 6;
  const int b0 = blockIdx.x * 8;
  const float* src = Hin + (size_t)b0 * TEAM * PD;

  Ab[t] = attb[t];

  #pragma unroll
  for (int f = 0; f < 12; ++f) {
    const int g     = t + f * 256;
    const int sg    = (g & 1) * 4;
    const int lane_ = (g >> 1) & 63;
    const int kt_   = (g >> 7) & 7;
    const int mt_   = g >> 10;
    const int p     = mt_ * 16 + (lane_ & 15);
    const int k     = kt_ * 32 + ((lane_ >> 4) << 3) + sg;
    float4 a4 = make_float4(0.f, 0.f, 0.f, 0.f);
    if (p < 40) a4 = *reinterpret_cast<const float4*>(src + (size_t)p * PD + k);
    float pv[4] = {a4.x, a4.y, a4.z, a4.w};
    short hi[4], lo[4];
    #pragma unroll
    for (int e = 0; e < 4; ++e) tsplit(pv[e], hi[e], lo[e]);
    const int off = ((mt_*8 + kt_)*64 + lane_)*8 + sg;
    *reinterpret_cast<short4*>(&Hf[off])         = make_short4(hi[0],hi[1],hi[2],hi[3]);
    *reinterpret_cast<short4*>(&Hf[12288 + off]) = make_short4(lo[0],lo[1],lo[2],lo[3]);
  }
  __syncthreads();

  f32x4 acc[3][4];
  #pragma unroll
  for (int mt = 0; mt < 3; ++mt)
    #pragma unroll
    for (int j = 0; j < 4; ++j) acc[mt][j] = (f32x4){0.f,0.f,0.f,0.f};

  const s16x8* Bh = reinterpret_cast<const s16x8*>(attf);
  #pragma unroll
  for (int kt = 0; kt < 8; ++kt) {
    s16x8 ah[3], al[3];
    #pragma unroll
    for (int mt = 0; mt < 3; ++mt) {
      ah[mt] = *reinterpret_cast<const s16x8*>(&Hf[((mt*8 + kt)*64 + lane)*8]);
      al[mt] = *reinterpret_cast<const s16x8*>(&Hf[12288 + ((mt*8 + kt)*64 + lane)*8]);
    }
    #pragma unroll
    for (int j = 0; j < 4; ++j) {
      const int nt = w * 4 + j;
      const s16x8 bh = Bh[(nt*8 + kt)*64 + lane];
      const s16x8 bl = Bh[8192 + (nt*8 + kt)*64 + lane];
      #pragma unroll
      for (int mt = 0; mt < 3; ++mt) {
        acc[mt][j] = __builtin_amdgcn_mfma_f32_16x16x32_bf16(ah[mt], bh, acc[mt][j], 0,0,0);
        acc[mt][j] = __builtin_amdgcn_mfma_f32_16x16x32_bf16(al[mt], bh, acc[mt][j], 0,0,0);
        acc[mt][j] = __builtin_amdgcn_mfma_f32_16x16x32_bf16(ah[mt], bl, acc[mt][j], 0,0,0);
      }
    }
  }
  __syncthreads();

  #pragma unroll
  for (int mt = 0; mt < 3; ++mt)
    #pragma unroll
    for (int j = 0; j < 4; ++j) {
      const int n = w * 64 + j * 16 + (lane & 15);
      #pragma unroll
      for (int r = 0; r < 4; ++r) {
        const int row = mt * 16 + ((lane >> 4) << 2) + r;
        if (row < 40) WAl[row * 260 + n] = acc[mt][j][r] + Ab[n];
      }
    }
  __syncthreads();

  #pragma unroll
  for (int qq = 0; qq < 2; ++qq) {
    const int q = w * 2 + qq;
    #pragma unroll
    for (int p = 0; p < NPAIR; ++p) {
      const int i1 = p >> 2, jj = p & 3;
      const int i2 = jj + (jj >= i1 ? 1 : 0);
      const float4 a4 = *reinterpret_cast<const float4*>(WAl + (q*TEAM + i1) * 260 + lane * 4);
      const float4 b4 = *reinterpret_cast<const float4*>(src + (size_t)(q*TEAM + i2) * PD + lane * 4);
      float v = a4.x*b4.x + a4.y*b4.y + a4.z*b4.z + a4.w*b4.w;
      #pragma unroll
      for (int off = 32; off > 0; off >>= 1) v += __shfl_xor(v, off);
      if (lane == 0) SC[(size_t)(b0 + q) * NPAIR + p] = v;
    }
  }
}

// ---------------------------------------------------------------------------
// Kernel C (round-18): pair MLP at NCHUNK=2 -- the untested middle of the
// chunk axis. cy in {0,1} halves columns per block: acc[5][4] = 80 acc regs
// -> the 124-VGPR class (k_l1/k_l2 measured) -> 4 waves/SIMD possible.
// Hl dropped (41.6 KB) so LDS ~24 KB -> 6-block LDS limit -> reg-limited
// 4 blocks/CU = 2x prior occupancy. Staging = r5-validated direct cooperative
// global reads (cy-paired blocks share the 40 KB H slice -> L2 reuse).
// Cost: staging+H-reads 2x total; benefit: 16 waves/CU overlap staging with
// MFMA across blocks. Tripwires: WRITE>50 MB = spill; Occupancy stuck at
// ~22% = limit miscounted -> revert to r7 k_mlp (187 us) as final.
// ---------------------------------------------------------------------------
__global__ __launch_bounds__(256) void k_mlp(
    const float* __restrict__ Hin, const short* __restrict__ w1f,
    const float* __restrict__ b1, const float* __restrict__ w2,
    float* __restrict__ PART)
{
  __shared__ short Af[10240];       // 20.5 KB (hi at 0, lo at +5120)
  __shared__ float Wb[256];
  __shared__ float Ww[256];
  __shared__ float red[320];

  const int t    = threadIdx.x;
  const int lane = t & 63;
  const int w    = t >> 6;
  const int blkx = blockIdx.x;
  const int cy   = blockIdx.y;
  const int b0   = blkx * 8;
  const float* src = Hin + (size_t)b0 * TEAM * PD;

  Wb[t & 255] = b1[cy * 256 + (t & 255)];
  Ww[t & 255] = w2[cy * 256 + (t & 255)];

  // hoisted staging geometry (invariant per thread; mt_ == f)
  const int sg    = (t & 1) * 4;
  const int lane_ = (t >> 1) & 63;
  const int ks_   = (t >> 7) & 1;
  const int kb    = ks_ * 32 + ((lane_ >> 4) << 3) + sg;
  int rowA[5], rowB[5], aof[5];
  #pragma unroll
  for (int f = 0; f < 5; ++f) {
    const int r  = f * 16 + (lane_ & 15);       // pair-row 0..79
    const int q  = r / UPAIR;
    const int p  = r - q * UPAIR;
    const int i1 = (p >= 4) + (p >= 7) + (p >= 9);
    const int i2 = p - (i1 * (9 - i1)) / 2 + i1 + 1;
    rowA[f] = (q * TEAM + i1) * PD;
    rowB[f] = (q * TEAM + i2) * PD;
    aof[f]  = (f * 2 + ks_) * 512 + lane_ * 8 + sg;
  }

  f32x4 acc[5][4];
  #pragma unroll
  for (int mt = 0; mt < 5; ++mt)
    #pragma unroll
    for (int j = 0; j < 4; ++j) acc[mt][j] = (f32x4){0.f,0.f,0.f,0.f};

  const s16x8* Bh = reinterpret_cast<const s16x8*>(w1f);
  const s16x8* Bl = reinterpret_cast<const s16x8*>(w1f + 131072);
  const int nt0 = cy * 16 + w * 4;    // 2 cy x 4 waves x 4 j = 32 nt = N=512

  for (int kt = 0; kt < 8; ++kt) {
    const int kc = kt >> 1, ks = kt & 1;
    if (ks == 0) {
      __syncthreads();                // prev chunk reads done
      const int kk = kc * 64 + kb;
      #pragma unroll
      for (int f = 0; f < 5; ++f) {
        const float4 a4 = *reinterpret_cast<const float4*>(src + rowA[f] + kk);
        const float4 b4 = *reinterpret_cast<const float4*>(src + rowB[f] + kk);
        float pv[4] = {a4.x*b4.x, a4.y*b4.y, a4.z*b4.z, a4.w*b4.w};
        short hi[4], lo[4];
        #pragma unroll
        for (int e = 0; e < 4; ++e) tsplit(pv[e], hi[e], lo[e]);
        *reinterpret_cast<short4*>(&Af[aof[f]])        = make_short4(hi[0],hi[1],hi[2],hi[3]);
        *reinterpret_cast<short4*>(&Af[5120 + aof[f]]) = make_short4(lo[0],lo[1],lo[2],lo[3]);
      }
      __syncthreads();
    }

    s16x8 ah[5], al[5];
    #pragma unroll
    for (int mt = 0; mt < 5; ++mt) {
      ah[mt] = *reinterpret_cast<const s16x8*>(&Af[(mt*2 + ks)*512 + lane*8]);
      al[mt] = *reinterpret_cast<const s16x8*>(&Af[5120 + (mt*2 + ks)*512 + lane*8]);
    }
    #pragma unroll
    for (int j = 0; j < 4; ++j) {
      const s16x8 bh = Bh[((nt0 + j)*8 + kt)*64 + lane];
      const s16x8 bl = Bl[((nt0 + j)*8 + kt)*64 + lane];
      #pragma unroll
      for (int mt = 0; mt < 5; ++mt) {
        acc[mt][j] = __builtin_amdgcn_mfma_f32_16x16x32_bf16(ah[mt], bh, acc[mt][j], 0,0,0);
        acc[mt][j] = __builtin_amdgcn_mfma_f32_16x16x32_bf16(ah[mt], bl, acc[mt][j], 0,0,0);
        acc[mt][j] = __builtin_amdgcn_mfma_f32_16x16x32_bf16(al[mt], bh, acc[mt][j], 0,0,0);
      }
    }
  }

  __syncthreads();

  // epilogue: silu + w2 dot over this block's 256 cols, 16-lane tree,
  // 4-wave reduce; PART is per-cy partial (k_final sums NCHUNK=2 chunks).
  const int colbase = w * 64 + (lane & 15);
  #pragma unroll
  for (int mt = 0; mt < 5; ++mt)
    #pragma unroll
    for (int r = 0; r < 4; ++r) {
      float s = 0.0f;
      #pragma unroll
      for (int j = 0; j < 4; ++j) {
        const int c = colbase + j * 16;
        s += silu_f(acc[mt][j][r] + Wb[c]) * Ww[c];
      }
      s += __shfl_xor(s, 1); s += __shfl_xor(s, 2);
      s += __shfl_xor(s, 4); s += __shfl_xor(s, 8);
      if ((lane & 15) == 0) {
        const int row = mt * 16 + ((lane >> 4) << 2) + r;
        red[row * 4 + w] = s;
      }
    }
  __syncthreads();
  if (t < 80) {
    const float s = red[t*4] + red[t*4+1] + red[t*4+2] + red[t*4+3];
    PART[(size_t)cy * (NB*UPAIR) + (size_t)blkx * 80 + t] = s;
  }
}

// ---------------------------------------------------------------------------
// Kernel D: one thread per batch (NCHUNK=2: sums the two cy partials).
// ---------------------------------------------------------------------------
__global__ void k_final(const float* __restrict__ SC, const float* __restrict__ PART,
                        const float* __restrict__ mb2, float* __restrict__ out)
{
  const int b = blockIdx.x * 256 + threadIdx.x;
  if (b >= NB) return;
  const float bias2 = mb2[0];
  float ord[UPAIR];
  #pragma unroll
  for (int u = 0; u < UPAIR; ++u) {
    float s = bias2;
    #pragma unroll
    for (int g = 0; g < NCHUNK; ++g) s += PART[(size_t)g * (NB*UPAIR) + (size_t)b * UPAIR + u];
    ord[u] = s;
  }
  float sc[NPAIR];
  #pragma unroll
  for (int p = 0; p < NPAIR; ++p) sc[p] = SC[(size_t)b * NPAIR + p];

  float res = 0.0f;
  #pragma unroll
  for (int i = 0; i < TEAM; ++i) {
    float m = sc[4*i];
    #pragma unroll
    for (int jj = 1; jj < 4; ++jj) m = fmaxf(m, sc[4*i + jj]);
    float e[4], d = 0.0f;
    #pragma unroll
    for (int jj = 0; jj < 4; ++jj) { e[jj] = __expf(sc[4*i + jj] - m); d += e[jj]; }
    const float inv = 1.0f / d;
    #pragma unroll
    for (int jj = 0; jj < 4; ++jj) {
      const int i2 = jj + (jj >= i ? 1 : 0);
      const int a  = i < i2 ? i : i2;
      const int bb = i < i2 ? i2 : i;
      const int u  = (a * (9 - a)) / 2 + (bb - a - 1);
      res += ord[u] * e[jj] * inv;
    }
  }
  out[b] = res;
}

// ---------------------------------------------------------------------------
extern "C" void kernel_launch(void* const* d_in, const int* in_sizes, int n_in,
                              void* d_out, int out_size, void* d_ws, size_t ws_size,
                              hipStream_t stream)
{
  (void)in_sizes; (void)n_in; (void)out_size;
  const int*   tids = (const int*)  d_in[0];
  const float* emb  = (const float*)d_in[1];
  const float* fw1  = (const float*)d_in[2];
  const float* fb1  = (const float*)d_in[3];
  const float* fw2  = (const float*)d_in[4];
  const float* fb2  = (const float*)d_in[5];
  const float* attw = (const float*)d_in[6];
  const float* attb = (const float*)d_in[7];
  const float* mw1  = (const float*)d_in[8];
  const float* mb1  = (const float*)d_in[9];
  const float* mw2  = (const float*)d_in[10];
  const float* mb2  = (const float*)d_in[11];
  float* out = (float*)d_out;

  float* H     = (float*)d_ws;                        // 81920*256 f32 = 84 MB
  float* SC    = H + (size_t)NPLAY * PD;              // NB*20 f32
  float* PART  = SC + (size_t)NB * NPAIR;             // NCHUNK*NB*10 f32
  short* w1f_m = (short*)(PART + (size_t)NCHUNK * NB * UPAIR); // mlp_w1 packed
  short* w1f_f = w1f_m + 262144;                      // fm_w1 packed
  short* w2f_f = w1f_f + 262144;                      // fm_w2 packed
  short* attf  = w2f_f + 262144;                      // att_w packed
  float* Hh1   = (float*)(attf + 131072);             // 81920*512 f32 = 168 MB
  const size_t NEED = (size_t)((char*)(Hh1 + (size_t)NPLAY * H1D) - (char*)d_ws);

  k_pack<<<512, 256, 0, stream>>>(mw1, w1f_m, 8, 131072);   // 512x256
  k_pack<<<512, 256, 0, stream>>>(fw1, w1f_f, 8, 131072);   // 512x256
  k_pack<<<512, 256, 0, stream>>>(fw2, w2f_f, 16, 131072);  // 256x512
  k_pack<<<256, 256, 0, stream>>>(attw, attf, 8, 65536);    // 256x256

  if (ws_size >= NEED) {
    k_l1<<<dim3(NPLAY/80, 2), 256, 0, stream>>>(tids, emb, w1f_f, fb1, Hh1);
    k_l2<<<NPLAY/80, 256, 0, stream>>>(Hh1, w2f_f, fb2, H);
  } else {
    k_fm4<<<NPLAY/32, 256, 0, stream>>>(tids, emb, w1f_f, fb1, w2f_f, fb2, H);
  }
  k_score<<<NB/8, 256, 0, stream>>>(H, attf, attb, SC);
  k_mlp<<<dim3(NB/8, 2), 256, 0, stream>>>(H, w1f_m, mb1, mw2, PART);
  k_final<<<NB/256, 256, 0, stream>>>(SC, PART, mb2, out);
}